// Round 5
// baseline (160.879 us; speedup 1.0000x reference)
//
#include <hip/hip_runtime.h>
#include <hip/hip_bf16.h>
#include <cstddef>

#define B_ 8
#define H_ 12
#define N_ 2048
#define D_ 64
#define M_ 256
#define BH_ (B_*H_)

typedef __attribute__((ext_vector_type(8))) short short8v;
typedef __attribute__((ext_vector_type(4))) float f32x4;
typedef __attribute__((address_space(3))) unsigned int lds_u32_t;
typedef __attribute__((address_space(1))) const unsigned int glb_u32_t;

static __device__ __forceinline__ float4 ld4(const float* p){ return *(const float4*)p; }

static __device__ __forceinline__ unsigned short f2bf(float x){
    union { float f; unsigned int u; } v; v.f = x;
    unsigned int r = v.u + 0x7FFFu + ((v.u >> 16) & 1u);
    return (unsigned short)(r >> 16);
}
static __device__ __forceinline__ unsigned int pack2(float a, float b){
    return (unsigned int)f2bf(a) | ((unsigned int)f2bf(b) << 16);
}
static __device__ __forceinline__ void gload_lds16(const void* g, void* l){
    __builtin_amdgcn_global_load_lds((glb_u32_t*)g, (lds_u32_t*)l, 16, 0, 0);
}

// ---------------- K0b: Dct fp32 -> DctB bf16 [256][2048] + DctT bf16 [2048][256]
__global__ __launch_bounds__(256)
void dct_prep_kernel(const float* __restrict__ Dct, unsigned short* __restrict__ DctB,
                     unsigned short* __restrict__ DctT)
{
    __shared__ __align__(16) unsigned short T[64*72];
    const int n0 = blockIdx.x * 64, m0 = blockIdx.y * 64;
    const int tid = threadIdx.x;
    const int m = tid >> 2, ng = tid & 3;
    unsigned short h[16];
    #pragma unroll
    for (int j = 0; j < 4; ++j) {
        const float4 t = ld4(Dct + (size_t)(m0+m)*N_ + n0 + ng*16 + j*4);
        h[4*j+0]=f2bf(t.x); h[4*j+1]=f2bf(t.y); h[4*j+2]=f2bf(t.z); h[4*j+3]=f2bf(t.w);
    }
    unsigned int w[8];
    #pragma unroll
    for (int j = 0; j < 8; ++j) w[j] = (unsigned int)h[2*j] | ((unsigned int)h[2*j+1]<<16);
    unsigned short* db = DctB + (size_t)(m0+m)*N_ + n0 + ng*16;
    *(uint4*)db = *(uint4*)&w[0];
    *(uint4*)(db+8) = *(uint4*)&w[4];
    #pragma unroll
    for (int j = 0; j < 16; ++j) T[(ng*16+j)*72 + m] = h[j];
    __syncthreads();
    const int n = tid >> 2, mg = tid & 3;
    uint4 a  = *(uint4*)&T[n*72 + mg*16];
    uint4 b2 = *(uint4*)&T[n*72 + mg*16 + 8];
    unsigned short* dt = DctT + (size_t)(n0+n)*M_ + m0 + mg*16;
    *(uint4*)dt = a; *(uint4*)(dt+8) = b2;
}

// ---------------- K1: Qd/Kd/Vd = DctB @ (scaled/masked X), MFMA bf16 ----------
// 1D grid 1152 (XCD-swizzled; 4 mtiles of one (bh,tz) adjacent on one XCD),
// 256 threads (4 waves), tile 64m x 64d, BK=64, dbuf LDS = 32 KB -> 5 blocks/CU.
__global__ __launch_bounds__(256, 5)
void gemm_qkv(const float* __restrict__ Q, const float* __restrict__ K,
              const float* __restrict__ V, const float* __restrict__ mask,
              const unsigned short* __restrict__ DctB,
              float* __restrict__ Qd, float* __restrict__ Kd, float* __restrict__ Vd)
{
    __shared__ __align__(16) unsigned short Asw[2][64*64];  // 2 x 8 KB, row 128 B, swz (r&7)<<4
    __shared__ __align__(16) unsigned short Bsw[2][64*64];  // 2 x 8 KB, row 128 B, swz ((d>>1)&7)<<4
    const int wg = blockIdx.x;
    const int id = (wg & 7) * 144 + (wg >> 3);   // 1152 = 8 XCD chunks x 144
    const int mt  = id & 3;                      // 4 mtiles of same (bh,tz) adjacent
    const int bhz = id >> 2;                     // 0..287
    const int bh  = bhz % BH_;
    const int tz  = bhz / BH_;
    const int b   = bh / H_;
    const float scale = 0.35355339059327373f;
    const float* X; float* Y; float smul; int um;
    if (tz==0)      { X=Q; Y=Qd; smul=scale; um=0; }
    else if (tz==1) { X=K; Y=Kd; smul=scale; um=1; }
    else            { X=V; Y=Vd; smul=1.0f;  um=1; }
    X += (size_t)bh*N_*D_;
    Y += (size_t)bh*M_*D_ + (size_t)mt*64*D_;
    const int m0 = mt*64;

    const int tid  = threadIdx.x;
    const int lane = tid & 63, wave = tid >> 6;
    // B staging: thread covers 4 k rows (kq) x 4 d cols (d0..d0+3)
    const int d0 = (tid & 15) * 4, kq = tid >> 4;
    // A staging (global_load_lds, pre-swizzled source): per instr lane -> row R0+(lane>>3)
    const int ar = lane >> 3;
    const int ac = (lane & 7) ^ ar;              // chunk: slot ^ (row&7), R0%8==0
    const unsigned short* abase = DctB + (size_t)(m0 + wave*16 + ar) * N_ + ac*8;

    f32x4 acc[4];
    #pragma unroll
    for (int j = 0; j < 4; ++j) { acc[j].x=0.f; acc[j].y=0.f; acc[j].z=0.f; acc[j].w=0.f; }

    float xb[4][4];   // [k row][d col]
    float fm[4];      // per-k scale factor

    #define STAGE_A(BUF, K0) do {                                             \
        gload_lds16(abase + (K0),              (char*)&Asw[BUF][0] + (wave*16)*128);   \
        gload_lds16(abase + (size_t)8*N_ + (K0), (char*)&Asw[BUF][0] + (wave*16+8)*128); \
    } while(0)

    #define LOAD_B(K0) do {                                                   \
        _Pragma("unroll")                                                     \
        for (int i_ = 0; i_ < 4; ++i_) {                                      \
            const float4 t_ = ld4(X + (size_t)((K0) + kq*4 + i_)*D_ + d0);    \
            xb[i_][0]=t_.x; xb[i_][1]=t_.y; xb[i_][2]=t_.z; xb[i_][3]=t_.w;   \
        }                                                                     \
        if (um) {                                                             \
            const float4 mv_ = ld4(mask + (size_t)b*N_ + (K0) + kq*4);        \
            fm[0]=smul*mv_.x; fm[1]=smul*mv_.y; fm[2]=smul*mv_.z; fm[3]=smul*mv_.w; \
        } else { fm[0]=smul; fm[1]=smul; fm[2]=smul; fm[3]=smul; }            \
    } while(0)

    #define WRITE_B(BUF) do {                                                 \
        _Pragma("unroll")                                                     \
        for (int j_ = 0; j_ < 4; ++j_) {                                      \
            const int d_ = d0 + j_;                                           \
            uint2 w_;                                                         \
            w_.x = pack2(xb[0][j_]*fm[0], xb[1][j_]*fm[1]);                   \
            w_.y = pack2(xb[2][j_]*fm[2], xb[3][j_]*fm[3]);                   \
            *(uint2*)((char*)&Bsw[BUF][0] + d_*128 + ((kq*8) ^ (((d_>>1)&7)<<4))) = w_; \
        }                                                                     \
    } while(0)

    #define COMPUTE(BUF) do {                                                 \
        _Pragma("unroll")                                                     \
        for (int kh_ = 0; kh_ < 2; ++kh_) {                                   \
            const int colb_ = kh_*64 + (lane>>4)*16;                          \
            const int r_ = wave*16 + (lane&15);                               \
            const short8v a_ = *(const short8v*)((char*)&Asw[BUF][0] + r_*128 + (colb_ ^ ((r_&7)<<4))); \
            _Pragma("unroll")                                                 \
            for (int nf_ = 0; nf_ < 4; ++nf_) {                               \
                const int rr_ = nf_*16 + (lane&15);                           \
                const short8v b_ = *(const short8v*)((char*)&Bsw[BUF][0] + rr_*128 + (colb_ ^ (((rr_>>1)&7)<<4))); \
                acc[nf_] = __builtin_amdgcn_mfma_f32_16x16x32_bf16(a_, b_, acc[nf_], 0, 0, 0); \
            }                                                                 \
        }                                                                     \
    } while(0)

    // prologue
    LOAD_B(0);
    STAGE_A(0, 0);
    WRITE_B(0);
    __syncthreads();

    int buf = 0;
    for (int t = 0; t < 32; ++t) {
        if (t < 31) {
            LOAD_B((t+1)*64);
            STAGE_A(buf^1, (t+1)*64);
        }
        COMPUTE(buf);
        if (t < 31) WRITE_B(buf^1);
        __syncthreads();
        buf ^= 1;
    }

    // epilogue: col = lane&15 (d), row = (lane>>4)*4 + r (m)
    #pragma unroll
    for (int nf = 0; nf < 4; ++nf)
        #pragma unroll
        for (int r = 0; r < 4; ++r) {
            const int m = wave*16 + (lane>>4)*4 + r;
            const int d = nf*16 + (lane&15);
            Y[(size_t)m*D_ + d] = acc[nf][r];
        }
    #undef STAGE_A
    #undef LOAD_B
    #undef WRITE_B
    #undef COMPUTE
}

// ---------------- K2: fused energy -> softmax -> ctx (fp32), bf16 transposed out
__global__ __launch_bounds__(256)
void attn_kernel(const float* __restrict__ Qd, const float* __restrict__ Kd,
                 const float* __restrict__ Vd, unsigned short* __restrict__ CtxT)
{
    __shared__ __align__(16) float S[M_][D_];    // 64 KB
    const int mt = blockIdx.x;
    const int bh = blockIdx.y;
    const float* qd = Qd + (size_t)bh * M_ * D_;
    const float* kd = Kd + (size_t)bh * M_ * D_;
    const float* vd = Vd + (size_t)bh * M_ * D_;

    const int tid = threadIdx.x;
    const int r = tid >> 2, sub = tid & 3;
    const int m = mt * 64 + r;

    float q[64];
    #pragma unroll
    for (int g = 0; g < 16; ++g) {
        const float4 t = ld4(qd + (size_t)m * D_ + g*4);
        q[4*g+0] = t.x; q[4*g+1] = t.y; q[4*g+2] = t.z; q[4*g+3] = t.w;
    }

    #pragma unroll
    for (int it = 0; it < 16; ++it) {
        const int i = tid + it*256;
        const int k = i >> 4, g = i & 15;
        const float4 t = ld4(kd + (size_t)i * 4);
        *(float4*)(&S[k][(g ^ (k & 3)) * 4]) = t;
    }
    __syncthreads();

    float e[64];
    #pragma unroll
    for (int kk = 0; kk < 64; ++kk) {
        const int k = kk*4 + sub;
        float acc = 0.f;
        #pragma unroll
        for (int g = 0; g < 16; ++g) {
            const float4 t = ld4(&S[k][(g ^ sub) * 4]);
            acc = fmaf(q[4*g+0], t.x, acc);
            acc = fmaf(q[4*g+1], t.y, acc);
            acc = fmaf(q[4*g+2], t.z, acc);
            acc = fmaf(q[4*g+3], t.w, acc);
        }
        e[kk] = acc;
    }

    float mx = e[0];
    #pragma unroll
    for (int kk = 1; kk < 64; ++kk) mx = fmaxf(mx, e[kk]);
    mx = fmaxf(mx, __shfl_xor(mx, 1));
    mx = fmaxf(mx, __shfl_xor(mx, 2));
    float sum = 0.f;
    #pragma unroll
    for (int kk = 0; kk < 64; ++kk) { e[kk] = __expf(e[kk] - mx); sum += e[kk]; }
    sum += __shfl_xor(sum, 1);
    sum += __shfl_xor(sum, 2);
    const float inv = 1.0f / sum;

    __syncthreads();
    #pragma unroll
    for (int it = 0; it < 16; ++it) {
        const int i = tid + it*256;
        const int k = i >> 4, g = i & 15;
        const float4 t = ld4(vd + (size_t)i * 4);
        *(float4*)(&S[k][(g ^ (k & 3)) * 4]) = t;
    }
    __syncthreads();

    float c[64] = {};
    #pragma unroll
    for (int kk = 0; kk < 64; ++kk) {
        const int k = kk*4 + sub;
        const float a = e[kk];
        #pragma unroll
        for (int g = 0; g < 16; ++g) {
            const float4 t = ld4(&S[k][(g ^ sub) * 4]);
            c[4*g+0] = fmaf(a, t.x, c[4*g+0]);
            c[4*g+1] = fmaf(a, t.y, c[4*g+1]);
            c[4*g+2] = fmaf(a, t.z, c[4*g+2]);
            c[4*g+3] = fmaf(a, t.w, c[4*g+3]);
        }
    }
    #pragma unroll
    for (int d = 0; d < 64; ++d) {
        c[d] += __shfl_xor(c[d], 1);
        c[d] += __shfl_xor(c[d], 2);
    }

    __syncthreads();
    unsigned short* T = (unsigned short*)&S[0][0];   // [64 d][72 m] ushorts
    #pragma unroll
    for (int g = 0; g < 16; ++g) {
        const int d = sub*16 + g;
        T[d*72 + r] = f2bf(c[d]*inv);
    }
    __syncthreads();
    const int d2 = tid >> 2, mg = tid & 3;
    uint4 w0 = *(uint4*)&T[d2*72 + mg*16];
    uint4 w1 = *(uint4*)&T[d2*72 + mg*16 + 8];
    unsigned short* dst = CtxT + (size_t)bh*D_*M_ + (size_t)d2*M_ + mt*64 + mg*16;
    *(uint4*)dst = w0; *(uint4*)(dst+8) = w1;
}

// ---------------- K3: x = DctT @ ctx_t^T, MFMA bf16 ------------------------
__global__ __launch_bounds__(128, 2)
void gemm_out(const unsigned short* __restrict__ DctT, const unsigned short* __restrict__ CtxT,
              float* __restrict__ Out)
{
    __shared__ __align__(16) unsigned short Asw[128*64];
    __shared__ __align__(16) unsigned short Bsw[64*64];
    const int nt = blockIdx.x, bh = blockIdx.y;
    const int n0 = nt*128;
    const unsigned short* ct = CtxT + (size_t)bh*D_*M_;
    float* out = Out + (size_t)bh*N_*D_;
    const int tid = threadIdx.x;
    const int lane = tid & 63, wave = tid >> 6;

    f32x4 acc[4][4];
    #pragma unroll
    for (int i = 0; i < 4; ++i)
        #pragma unroll
        for (int j = 0; j < 4; ++j) { acc[i][j].x=0.f; acc[i][j].y=0.f; acc[i][j].z=0.f; acc[i][j].w=0.f; }

    for (int step = 0; step < 4; ++step) {
        const int k0 = step*64;
        if (step) __syncthreads();
        const int ch = tid & 7;
        #pragma unroll
        for (int rr = 0; rr < 8; ++rr) {
            const int r = (tid>>3) + rr*16;
            const uint4 v = *(const uint4*)(DctT + (size_t)(n0+r)*M_ + k0 + ch*8);
            *(uint4*)((char*)Asw + r*128 + ((ch*16) ^ ((r&7)<<4))) = v;
        }
        #pragma unroll
        for (int rr = 0; rr < 4; ++rr) {
            const int d = (tid>>3) + rr*16;
            const uint4 v = *(const uint4*)(ct + (size_t)d*M_ + k0 + ch*8);
            *(uint4*)((char*)Bsw + d*128 + ((ch*16) ^ (((d>>1)&7)<<4))) = v;
        }
        __syncthreads();
        #pragma unroll
        for (int kh = 0; kh < 2; ++kh) {
            const int colb = kh*64 + (lane>>4)*16;
            short8v a[4], bb[4];
            #pragma unroll
            for (int mf = 0; mf < 4; ++mf) {
                const int r = wave*64 + mf*16 + (lane&15);
                a[mf] = *(const short8v*)((char*)Asw + r*128 + (colb ^ ((r&7)<<4)));
            }
            #pragma unroll
            for (int nf = 0; nf < 4; ++nf) {
                const int r = nf*16 + (lane&15);
                bb[nf] = *(const short8v*)((char*)Bsw + r*128 + (colb ^ (((r>>1)&7)<<4)));
            }
            #pragma unroll
            for (int mf = 0; mf < 4; ++mf)
                #pragma unroll
                for (int nf = 0; nf < 4; ++nf)
                    acc[mf][nf] = __builtin_amdgcn_mfma_f32_16x16x32_bf16(a[mf], bb[nf], acc[mf][nf], 0, 0, 0);
        }
    }
    #pragma unroll
    for (int mf = 0; mf < 4; ++mf)
        #pragma unroll
        for (int nf = 0; nf < 4; ++nf)
            #pragma unroll
            for (int r = 0; r < 4; ++r) {
                const int n = n0 + wave*64 + mf*16 + (lane>>4)*4 + r;
                const int d = nf*16 + (lane&15);
                out[(size_t)n*D_ + d] = acc[mf][nf][r];
            }
}

extern "C" void kernel_launch(void* const* d_in, const int* in_sizes, int n_in,
                              void* d_out, int out_size, void* d_ws, size_t ws_size,
                              hipStream_t stream) {
    const float* Q    = (const float*)d_in[0];
    const float* K    = (const float*)d_in[1];
    const float* V    = (const float*)d_in[2];
    const float* mask = (const float*)d_in[3];
    const float* Dct  = (const float*)d_in[4];
    float* out = (float*)d_out;

    const size_t per = (size_t)BH_ * M_ * D_;          // 1,572,864
    float* wsf = (float*)d_ws;
    float* Qd = wsf;
    float* Kd = Qd + per;
    float* Vd = Kd + per;
    unsigned short* CtxT = (unsigned short*)(Vd + per);  // per ushorts
    unsigned short* DctB = CtxT + per;                   // 524288
    unsigned short* DctT = DctB + (size_t)M_ * N_;       // 524288

    dct_prep_kernel<<<dim3(N_/64, M_/64), 256, 0, stream>>>(Dct, DctB, DctT);
    gemm_qkv<<<dim3(1152), 256, 0, stream>>>(Q, K, V, mask, DctB, Qd, Kd, Vd);
    attn_kernel<<<dim3(M_/64, BH_), 256, 0, stream>>>(Qd, Kd, Vd, CtxT);
    gemm_out<<<dim3(N_/128, BH_), 128, 0, stream>>>(DctT, CtxT, out);
}

// Round 6
// 158.377 us; speedup vs baseline: 1.0158x; 1.0158x over previous
//
#include <hip/hip_runtime.h>
#include <hip/hip_bf16.h>
#include <cstddef>

#define B_ 8
#define H_ 12
#define N_ 2048
#define D_ 64
#define M_ 256
#define BH_ (B_*H_)

typedef __attribute__((ext_vector_type(8))) short short8v;
typedef __attribute__((ext_vector_type(4))) float f32x4;

static __device__ __forceinline__ float4 ld4(const float* p){ return *(const float4*)p; }

static __device__ __forceinline__ unsigned short f2bf(float x){
    union { float f; unsigned int u; } v; v.f = x;
    unsigned int r = v.u + 0x7FFFu + ((v.u >> 16) & 1u);
    return (unsigned short)(r >> 16);
}
static __device__ __forceinline__ unsigned int pack2(float a, float b){
    return (unsigned int)f2bf(a) | ((unsigned int)f2bf(b) << 16);
}

// ---------------- K0b: Dct fp32 -> DctB bf16 [256][2048] + DctT bf16 [2048][256]
__global__ __launch_bounds__(256)
void dct_prep_kernel(const float* __restrict__ Dct, unsigned short* __restrict__ DctB,
                     unsigned short* __restrict__ DctT)
{
    __shared__ __align__(16) unsigned short T[64*72];
    const int n0 = blockIdx.x * 64, m0 = blockIdx.y * 64;
    const int tid = threadIdx.x;
    const int m = tid >> 2, ng = tid & 3;
    unsigned short h[16];
    #pragma unroll
    for (int j = 0; j < 4; ++j) {
        const float4 t = ld4(Dct + (size_t)(m0+m)*N_ + n0 + ng*16 + j*4);
        h[4*j+0]=f2bf(t.x); h[4*j+1]=f2bf(t.y); h[4*j+2]=f2bf(t.z); h[4*j+3]=f2bf(t.w);
    }
    unsigned int w[8];
    #pragma unroll
    for (int j = 0; j < 8; ++j) w[j] = (unsigned int)h[2*j] | ((unsigned int)h[2*j+1]<<16);
    unsigned short* db = DctB + (size_t)(m0+m)*N_ + n0 + ng*16;
    *(uint4*)db = *(uint4*)&w[0];
    *(uint4*)(db+8) = *(uint4*)&w[4];
    #pragma unroll
    for (int j = 0; j < 16; ++j) T[(ng*16+j)*72 + m] = h[j];
    __syncthreads();
    const int n = tid >> 2, mg = tid & 3;
    uint4 a  = *(uint4*)&T[n*72 + mg*16];
    uint4 b2 = *(uint4*)&T[n*72 + mg*16 + 8];
    unsigned short* dt = DctT + (size_t)(n0+n)*M_ + m0 + mg*16;
    *(uint4*)dt = a; *(uint4*)(dt+8) = b2;
}

// ---------------- K1: Qd/Kd/Vd = DctB @ (scaled/masked X), MFMA bf16 ----------
// 288 blocks = (bh, tz). 512 threads (8 waves). Each block computes the FULL
// 256m x 64d output for its panel and reads its X panel from memory EXACTLY
// once (read-once design: memory-side traffic = 147 MB floor). A (Dct bf16)
// is read per-fragment directly from global (L2-resident, shared by all).
// B: BK=128 per step as 2 x 64-row sub-tiles (thread-halves), R3's proven
// conflict-free ds_write_b128 pattern, double-buffered (32 KB LDS).
__global__ __launch_bounds__(512, 4)
void gemm_qkv(const float* __restrict__ Q, const float* __restrict__ K,
              const float* __restrict__ V, const float* __restrict__ mask,
              const unsigned short* __restrict__ DctB,
              float* __restrict__ Qd, float* __restrict__ Kd, float* __restrict__ Vd)
{
    __shared__ __align__(16) unsigned short Bsw[2][2][64*64];  // [buf][sub] 8 KB each = 32 KB
    const int wg = blockIdx.x;
    const int bh = wg % BH_;
    const int tz = wg / BH_;
    const int b  = bh / H_;
    const float scale = 0.35355339059327373f;
    const float* X; float* Y; float smul; int um;
    if (tz==0)      { X=Q; Y=Qd; smul=scale; um=0; }
    else if (tz==1) { X=K; Y=Kd; smul=scale; um=1; }
    else            { X=V; Y=Vd; smul=1.0f;  um=1; }
    X += (size_t)bh*N_*D_;
    Y += (size_t)bh*M_*D_;

    const int tid  = threadIdx.x;
    const int lane = tid & 63, wv = tid >> 6;     // 8 waves, wave owns rows [32*wv, 32*wv+32)
    const int sub  = tid >> 8;                    // k sub-tile 0/1 (rows k0+64*sub ..)
    const int g    = tid & 255;
    const int kseg = g >> 5;                      // 0..7 (8 k-rows each)
    const int d0   = (g & 31) * 2;                // d pair

    f32x4 acc[2][4];
    #pragma unroll
    for (int i = 0; i < 2; ++i)
        #pragma unroll
        for (int j = 0; j < 4; ++j) { acc[i][j].x=0.f; acc[i][j].y=0.f; acc[i][j].z=0.f; acc[i][j].w=0.f; }

    float2 xr[8];
    float  fm[8];

    // per-lane A base: row = wv*32 + (lane&15), k-slice start (lane>>4)*8
    const unsigned short* abase = DctB + (size_t)(wv*32 + (lane&15))*N_ + (lane>>4)*8;

    #define LOAD_B(K0) do {                                                   \
        const float* xp_ = X + (size_t)((K0) + sub*64 + kseg*8) * D_ + d0;    \
        _Pragma("unroll")                                                     \
        for (int i_ = 0; i_ < 8; ++i_) xr[i_] = *(const float2*)(xp_ + i_*D_);\
        if (um) {                                                             \
            const float* mp_ = mask + (size_t)b*N_ + (K0) + sub*64 + kseg*8;  \
            const float4 ma_ = ld4(mp_), mb_ = ld4(mp_ + 4);                  \
            fm[0]=smul*ma_.x; fm[1]=smul*ma_.y; fm[2]=smul*ma_.z; fm[3]=smul*ma_.w; \
            fm[4]=smul*mb_.x; fm[5]=smul*mb_.y; fm[6]=smul*mb_.z; fm[7]=smul*mb_.w; \
        } else {                                                              \
            _Pragma("unroll")                                                 \
            for (int i_ = 0; i_ < 8; ++i_) fm[i_] = smul;                     \
        }                                                                     \
    } while(0)

    #define WRITE_B(BUF) do {                                                 \
        float fa_[8], fb_[8];                                                 \
        _Pragma("unroll")                                                     \
        for (int i_ = 0; i_ < 8; ++i_) {                                      \
            fa_[i_] = xr[i_].x * fm[i_]; fb_[i_] = xr[i_].y * fm[i_];         \
        }                                                                     \
        uint4 w0_, w1_;                                                       \
        w0_.x=pack2(fa_[0],fa_[1]); w0_.y=pack2(fa_[2],fa_[3]);               \
        w0_.z=pack2(fa_[4],fa_[5]); w0_.w=pack2(fa_[6],fa_[7]);               \
        w1_.x=pack2(fb_[0],fb_[1]); w1_.y=pack2(fb_[2],fb_[3]);               \
        w1_.z=pack2(fb_[4],fb_[5]); w1_.w=pack2(fb_[6],fb_[7]);               \
        *(uint4*)((char*)&Bsw[BUF][sub][0] + d0*128     + ((kseg*16) ^ (((d0>>1)&7)<<4)))     = w0_; \
        *(uint4*)((char*)&Bsw[BUF][sub][0] + (d0+1)*128 + ((kseg*16) ^ ((((d0+1)>>1)&7)<<4))) = w1_; \
    } while(0)

    // COMPUTE over BK=128: kh 0..3 (32-k windows); A direct from global (L2-hot)
    #define COMPUTE(BUF, K0) do {                                             \
        _Pragma("unroll")                                                     \
        for (int kh_ = 0; kh_ < 4; ++kh_) {                                   \
            const int sb_ = kh_ >> 1;                                         \
            const int colb_ = (kh_&1)*64 + (lane>>4)*16;                      \
            short8v a_[2], b_[4];                                             \
            _Pragma("unroll")                                                 \
            for (int mf_ = 0; mf_ < 2; ++mf_)                                 \
                a_[mf_] = *(const short8v*)(abase + (size_t)(mf_*16)*N_ + (K0) + kh_*32); \
            _Pragma("unroll")                                                 \
            for (int nf_ = 0; nf_ < 4; ++nf_) {                               \
                const int rr_ = nf_*16 + (lane&15);                           \
                b_[nf_] = *(const short8v*)((char*)&Bsw[BUF][sb_][0] + rr_*128 + (colb_ ^ (((rr_>>1)&7)<<4))); \
            }                                                                 \
            _Pragma("unroll")                                                 \
            for (int mf_ = 0; mf_ < 2; ++mf_)                                 \
                _Pragma("unroll")                                             \
                for (int nf_ = 0; nf_ < 4; ++nf_)                             \
                    acc[mf_][nf_] = __builtin_amdgcn_mfma_f32_16x16x32_bf16(a_[mf_], b_[nf_], acc[mf_][nf_], 0, 0, 0); \
        }                                                                     \
    } while(0)

    // prologue
    LOAD_B(0);
    WRITE_B(0);
    __syncthreads();

    int buf = 0;
    for (int t = 0; t < 16; ++t) {
        if (t < 15) LOAD_B((t+1)*128);     // issue next X loads before compute
        COMPUTE(buf, t*128);               // A global loads + B LDS reads + 32 MFMA/wave
        if (t < 15) WRITE_B(buf^1);        // counted vmcnt wait on xr, then ds_write
        __syncthreads();
        buf ^= 1;
    }

    // epilogue: col = lane&15 (d), row = (lane>>4)*4 + r (m)
    #pragma unroll
    for (int mf = 0; mf < 2; ++mf)
        #pragma unroll
        for (int nf = 0; nf < 4; ++nf)
            #pragma unroll
            for (int r = 0; r < 4; ++r) {
                const int m = wv*32 + mf*16 + (lane>>4)*4 + r;
                const int d = nf*16 + (lane&15);
                Y[(size_t)m*D_ + d] = acc[mf][nf][r];
            }
    #undef LOAD_B
    #undef WRITE_B
    #undef COMPUTE
}

// ---------------- K2: fused energy -> softmax -> ctx (fp32), bf16 transposed out
__global__ __launch_bounds__(256)
void attn_kernel(const float* __restrict__ Qd, const float* __restrict__ Kd,
                 const float* __restrict__ Vd, unsigned short* __restrict__ CtxT)
{
    __shared__ __align__(16) float S[M_][D_];    // 64 KB
    const int mt = blockIdx.x;
    const int bh = blockIdx.y;
    const float* qd = Qd + (size_t)bh * M_ * D_;
    const float* kd = Kd + (size_t)bh * M_ * D_;
    const float* vd = Vd + (size_t)bh * M_ * D_;

    const int tid = threadIdx.x;
    const int r = tid >> 2, sub = tid & 3;
    const int m = mt * 64 + r;

    float q[64];
    #pragma unroll
    for (int g = 0; g < 16; ++g) {
        const float4 t = ld4(qd + (size_t)m * D_ + g*4);
        q[4*g+0] = t.x; q[4*g+1] = t.y; q[4*g+2] = t.z; q[4*g+3] = t.w;
    }

    #pragma unroll
    for (int it = 0; it < 16; ++it) {
        const int i = tid + it*256;
        const int k = i >> 4, g = i & 15;
        const float4 t = ld4(kd + (size_t)i * 4);
        *(float4*)(&S[k][(g ^ (k & 3)) * 4]) = t;
    }
    __syncthreads();

    float e[64];
    #pragma unroll
    for (int kk = 0; kk < 64; ++kk) {
        const int k = kk*4 + sub;
        float acc = 0.f;
        #pragma unroll
        for (int g = 0; g < 16; ++g) {
            const float4 t = ld4(&S[k][(g ^ sub) * 4]);
            acc = fmaf(q[4*g+0], t.x, acc);
            acc = fmaf(q[4*g+1], t.y, acc);
            acc = fmaf(q[4*g+2], t.z, acc);
            acc = fmaf(q[4*g+3], t.w, acc);
        }
        e[kk] = acc;
    }

    float mx = e[0];
    #pragma unroll
    for (int kk = 1; kk < 64; ++kk) mx = fmaxf(mx, e[kk]);
    mx = fmaxf(mx, __shfl_xor(mx, 1));
    mx = fmaxf(mx, __shfl_xor(mx, 2));
    float sum = 0.f;
    #pragma unroll
    for (int kk = 0; kk < 64; ++kk) { e[kk] = __expf(e[kk] - mx); sum += e[kk]; }
    sum += __shfl_xor(sum, 1);
    sum += __shfl_xor(sum, 2);
    const float inv = 1.0f / sum;

    __syncthreads();
    #pragma unroll
    for (int it = 0; it < 16; ++it) {
        const int i = tid + it*256;
        const int k = i >> 4, g = i & 15;
        const float4 t = ld4(vd + (size_t)i * 4);
        *(float4*)(&S[k][(g ^ (k & 3)) * 4]) = t;
    }
    __syncthreads();

    float c[64] = {};
    #pragma unroll
    for (int kk = 0; kk < 64; ++kk) {
        const int k = kk*4 + sub;
        const float a = e[kk];
        #pragma unroll
        for (int g = 0; g < 16; ++g) {
            const float4 t = ld4(&S[k][(g ^ sub) * 4]);
            c[4*g+0] = fmaf(a, t.x, c[4*g+0]);
            c[4*g+1] = fmaf(a, t.y, c[4*g+1]);
            c[4*g+2] = fmaf(a, t.z, c[4*g+2]);
            c[4*g+3] = fmaf(a, t.w, c[4*g+3]);
        }
    }
    #pragma unroll
    for (int d = 0; d < 64; ++d) {
        c[d] += __shfl_xor(c[d], 1);
        c[d] += __shfl_xor(c[d], 2);
    }

    __syncthreads();
    unsigned short* T = (unsigned short*)&S[0][0];   // [64 d][72 m] ushorts
    #pragma unroll
    for (int g = 0; g < 16; ++g) {
        const int d = sub*16 + g;
        T[d*72 + r] = f2bf(c[d]*inv);
    }
    __syncthreads();
    const int d2 = tid >> 2, mg = tid & 3;
    uint4 w0 = *(uint4*)&T[d2*72 + mg*16];
    uint4 w1 = *(uint4*)&T[d2*72 + mg*16 + 8];
    unsigned short* dst = CtxT + (size_t)bh*D_*M_ + (size_t)d2*M_ + mt*64 + mg*16;
    *(uint4*)dst = w0; *(uint4*)(dst+8) = w1;
}

// ---------------- K3: x = DctT @ ctx_t^T, MFMA bf16 ------------------------
__global__ __launch_bounds__(128, 2)
void gemm_out(const unsigned short* __restrict__ DctT, const unsigned short* __restrict__ CtxT,
              float* __restrict__ Out)
{
    __shared__ __align__(16) unsigned short Asw[128*64];
    __shared__ __align__(16) unsigned short Bsw[64*64];
    const int nt = blockIdx.x, bh = blockIdx.y;
    const int n0 = nt*128;
    const unsigned short* ct = CtxT + (size_t)bh*D_*M_;
    float* out = Out + (size_t)bh*N_*D_;
    const int tid = threadIdx.x;
    const int lane = tid & 63, wave = tid >> 6;

    f32x4 acc[4][4];
    #pragma unroll
    for (int i = 0; i < 4; ++i)
        #pragma unroll
        for (int j = 0; j < 4; ++j) { acc[i][j].x=0.f; acc[i][j].y=0.f; acc[i][j].z=0.f; acc[i][j].w=0.f; }

    for (int step = 0; step < 4; ++step) {
        const int k0 = step*64;
        if (step) __syncthreads();
        const int ch = tid & 7;
        #pragma unroll
        for (int rr = 0; rr < 8; ++rr) {
            const int r = (tid>>3) + rr*16;
            const uint4 v = *(const uint4*)(DctT + (size_t)(n0+r)*M_ + k0 + ch*8);
            *(uint4*)((char*)Asw + r*128 + ((ch*16) ^ ((r&7)<<4))) = v;
        }
        #pragma unroll
        for (int rr = 0; rr < 4; ++rr) {
            const int d = (tid>>3) + rr*16;
            const uint4 v = *(const uint4*)(ct + (size_t)d*M_ + k0 + ch*8);
            *(uint4*)((char*)Bsw + d*128 + ((ch*16) ^ (((d>>1)&7)<<4))) = v;
        }
        __syncthreads();
        #pragma unroll
        for (int kh = 0; kh < 2; ++kh) {
            const int colb = kh*64 + (lane>>4)*16;
            short8v a[4], bb[4];
            #pragma unroll
            for (int mf = 0; mf < 4; ++mf) {
                const int r = wave*64 + mf*16 + (lane&15);
                a[mf] = *(const short8v*)((char*)Asw + r*128 + (colb ^ ((r&7)<<4)));
            }
            #pragma unroll
            for (int nf = 0; nf < 4; ++nf) {
                const int r = nf*16 + (lane&15);
                bb[nf] = *(const short8v*)((char*)Bsw + r*128 + (colb ^ (((r>>1)&7)<<4)));
            }
            #pragma unroll
            for (int mf = 0; mf < 4; ++mf)
                #pragma unroll
                for (int nf = 0; nf < 4; ++nf)
                    acc[mf][nf] = __builtin_amdgcn_mfma_f32_16x16x32_bf16(a[mf], bb[nf], acc[mf][nf], 0, 0, 0);
        }
    }
    #pragma unroll
    for (int mf = 0; mf < 4; ++mf)
        #pragma unroll
        for (int nf = 0; nf < 4; ++nf)
            #pragma unroll
            for (int r = 0; r < 4; ++r) {
                const int n = n0 + wave*64 + mf*16 + (lane>>4)*4 + r;
                const int d = nf*16 + (lane&15);
                out[(size_t)n*D_ + d] = acc[mf][nf][r];
            }
}

extern "C" void kernel_launch(void* const* d_in, const int* in_sizes, int n_in,
                              void* d_out, int out_size, void* d_ws, size_t ws_size,
                              hipStream_t stream) {
    const float* Q    = (const float*)d_in[0];
    const float* K    = (const float*)d_in[1];
    const float* V    = (const float*)d_in[2];
    const float* mask = (const float*)d_in[3];
    const float* Dct  = (const float*)d_in[4];
    float* out = (float*)d_out;

    const size_t per = (size_t)BH_ * M_ * D_;          // 1,572,864
    float* wsf = (float*)d_ws;
    float* Qd = wsf;
    float* Kd = Qd + per;
    float* Vd = Kd + per;
    unsigned short* CtxT = (unsigned short*)(Vd + per);  // per ushorts
    unsigned short* DctB = CtxT + per;                   // 524288
    unsigned short* DctT = DctB + (size_t)M_ * N_;       // 524288

    dct_prep_kernel<<<dim3(N_/64, M_/64), 256, 0, stream>>>(Dct, DctB, DctT);
    gemm_qkv<<<dim3(3*BH_), 512, 0, stream>>>(Q, K, V, mask, DctB, Qd, Kd, Vd);
    attn_kernel<<<dim3(M_/64, BH_), 256, 0, stream>>>(Qd, Kd, Vd, CtxT);
    gemm_out<<<dim3(N_/128, BH_), 128, 0, stream>>>(DctT, CtxT, out);
}

// Round 7
// 133.038 us; speedup vs baseline: 1.2093x; 1.1905x over previous
//
#include <hip/hip_runtime.h>
#include <hip/hip_bf16.h>
#include <cstddef>

#define B_ 8
#define H_ 12
#define N_ 2048
#define D_ 64
#define M_ 256
#define BH_ (B_*H_)

typedef __attribute__((ext_vector_type(8))) short short8v;
typedef __attribute__((ext_vector_type(4))) float f32x4;
typedef __attribute__((address_space(3))) unsigned int lds_u32_t;
typedef __attribute__((address_space(1))) const unsigned int glb_u32_t;

static __device__ __forceinline__ float4 ld4(const float* p){ return *(const float4*)p; }

static __device__ __forceinline__ unsigned short f2bf(float x){
    union { float f; unsigned int u; } v; v.f = x;
    unsigned int r = v.u + 0x7FFFu + ((v.u >> 16) & 1u);
    return (unsigned short)(r >> 16);
}
static __device__ __forceinline__ unsigned int pack2(float a, float b){
    return (unsigned int)f2bf(a) | ((unsigned int)f2bf(b) << 16);
}
static __device__ __forceinline__ void gload_lds16(const void* g, void* l){
    __builtin_amdgcn_global_load_lds((glb_u32_t*)g, (lds_u32_t*)l, 16, 0, 0);
}

// ---------------- K0b: Dct fp32 -> DctB bf16 [256][2048] + DctT bf16 [2048][256]
__global__ __launch_bounds__(256)
void dct_prep_kernel(const float* __restrict__ Dct, unsigned short* __restrict__ DctB,
                     unsigned short* __restrict__ DctT)
{
    __shared__ __align__(16) unsigned short T[64*72];
    const int n0 = blockIdx.x * 64, m0 = blockIdx.y * 64;
    const int tid = threadIdx.x;
    const int m = tid >> 2, ng = tid & 3;
    unsigned short h[16];
    #pragma unroll
    for (int j = 0; j < 4; ++j) {
        const float4 t = ld4(Dct + (size_t)(m0+m)*N_ + n0 + ng*16 + j*4);
        h[4*j+0]=f2bf(t.x); h[4*j+1]=f2bf(t.y); h[4*j+2]=f2bf(t.z); h[4*j+3]=f2bf(t.w);
    }
    unsigned int w[8];
    #pragma unroll
    for (int j = 0; j < 8; ++j) w[j] = (unsigned int)h[2*j] | ((unsigned int)h[2*j+1]<<16);
    unsigned short* db = DctB + (size_t)(m0+m)*N_ + n0 + ng*16;
    *(uint4*)db = *(uint4*)&w[0];
    *(uint4*)(db+8) = *(uint4*)&w[4];
    #pragma unroll
    for (int j = 0; j < 16; ++j) T[(ng*16+j)*72 + m] = h[j];
    __syncthreads();
    const int n = tid >> 2, mg = tid & 3;
    uint4 a  = *(uint4*)&T[n*72 + mg*16];
    uint4 b2 = *(uint4*)&T[n*72 + mg*16 + 8];
    unsigned short* dt = DctT + (size_t)(n0+n)*M_ + m0 + mg*16;
    *(uint4*)dt = a; *(uint4*)(dt+8) = b2;
}

// ---------------- K1: Qd/Kd/Vd = DctB @ (scaled/masked X), MFMA bf16 ----------
// 288 blocks = (bh,tz), 512 threads (8 waves). Full 256m x 64d per block, X read
// exactly once. BK=64, 32 steps. A (Dct bf16) staged via global_load_lds with
// pre-swizzled source, double-buffered; each wave stages/reads only its own 32
// rows. B (X) reg-staged with DEPTH-2 X prefetch (two named reg sets).
// Counted barrier: s_waitcnt vmcnt(10) lgkmcnt(0) + raw s_barrier — X(t+2)'s 10
// loads stay in flight across the barrier; A-gloads are issued BEFORE X-loads
// (FENCE-pinned) so vmcnt(10) provably drains A(t+1).
__global__ __launch_bounds__(512, 2)
void gemm_qkv(const float* __restrict__ Q, const float* __restrict__ K,
              const float* __restrict__ V, const float* __restrict__ mask,
              const unsigned short* __restrict__ DctB,
              float* __restrict__ Qd, float* __restrict__ Kd, float* __restrict__ Vd)
{
    __shared__ __align__(16) unsigned short Asw[2][256*64];  // 2 x 32 KB, row 128 B, swz (r&7)<<4
    __shared__ __align__(16) unsigned short Bsw[2][64*64];   // 2 x 8 KB,  row 128 B, swz ((d>>1)&7)<<4
    const int wg = blockIdx.x;
    const int bh = wg % BH_;
    const int tz = wg / BH_;
    const int b  = bh / H_;
    const float scale = 0.35355339059327373f;
    const float* X; float* Y; float smul; int um;
    if (tz==0)      { X=Q; Y=Qd; smul=scale; um=0; }
    else if (tz==1) { X=K; Y=Kd; smul=scale; um=1; }
    else            { X=V; Y=Vd; smul=1.0f;  um=1; }
    X += (size_t)bh*N_*D_;
    Y += (size_t)bh*M_*D_;

    const int tid  = threadIdx.x;
    const int lane = tid & 63, wv = tid >> 6;   // 8 waves; wave owns m rows [32wv,32wv+32)
    // A staging: 4 gload_lds per wave per step, 8 rows each; pre-swizzled source
    const int ar = lane >> 3;
    const int ac = (lane & 7) ^ ar;
    const unsigned short* abase = DctB + (size_t)(wv*32 + ar)*N_ + ac*8;
    // B staging: wave wv covers k rows [8wv,8wv+8), lane covers d = lane
    const float* xcol = X + lane;
    const int bswz = ((lane>>1)&7)<<4;

    f32x4 acc[2][4];
    #pragma unroll
    for (int i = 0; i < 2; ++i)
        #pragma unroll
        for (int j = 0; j < 4; ++j) { acc[i][j].x=0.f; acc[i][j].y=0.f; acc[i][j].z=0.f; acc[i][j].w=0.f; }

    float  xrA[8], xrB[8];
    float4 mvA0, mvA1, mvB0, mvB1;

    #define A_GLOAD(BUF, K0) do {                                             \
        _Pragma("unroll")                                                     \
        for (int i_ = 0; i_ < 4; ++i_)                                        \
            gload_lds16(abase + (size_t)(i_*8)*N_ + (K0),                     \
                        (char*)&Asw[BUF][0] + (wv*32 + i_*8)*128);            \
    } while(0)

    #define X_LOAD(XR, M0, M1, K0) do {                                      \
        const float* xp_ = xcol + (size_t)((K0) + wv*8) * D_;                 \
        _Pragma("unroll")                                                     \
        for (int i_ = 0; i_ < 8; ++i_) XR[i_] = xp_[(size_t)i_*D_];           \
        const float* mp_ = mask + (size_t)b*N_ + (K0) + wv*8;                 \
        M0 = ld4(mp_); M1 = ld4(mp_ + 4);                                     \
    } while(0)

    #define WRITE_B(XR, M0, M1, BUF) do {                                    \
        float f_[8];                                                          \
        f_[0] = um ? smul*M0.x : smul;  f_[1] = um ? smul*M0.y : smul;        \
        f_[2] = um ? smul*M0.z : smul;  f_[3] = um ? smul*M0.w : smul;        \
        f_[4] = um ? smul*M1.x : smul;  f_[5] = um ? smul*M1.y : smul;        \
        f_[6] = um ? smul*M1.z : smul;  f_[7] = um ? smul*M1.w : smul;        \
        uint4 w_;                                                             \
        w_.x = pack2(XR[0]*f_[0], XR[1]*f_[1]);                               \
        w_.y = pack2(XR[2]*f_[2], XR[3]*f_[3]);                               \
        w_.z = pack2(XR[4]*f_[4], XR[5]*f_[5]);                               \
        w_.w = pack2(XR[6]*f_[6], XR[7]*f_[7]);                               \
        *(uint4*)((char*)&Bsw[BUF][0] + lane*128 + ((wv*16) ^ bswz)) = w_;    \
    } while(0)

    #define COMPUTE(BUF) do {                                                 \
        _Pragma("unroll")                                                     \
        for (int kh_ = 0; kh_ < 2; ++kh_) {                                   \
            const int colb_ = kh_*64 + (lane>>4)*16;                          \
            short8v a_[2], b_[4];                                             \
            _Pragma("unroll")                                                 \
            for (int mf_ = 0; mf_ < 2; ++mf_) {                               \
                const int r_ = wv*32 + mf_*16 + (lane&15);                    \
                a_[mf_] = *(const short8v*)((char*)&Asw[BUF][0] + r_*128 + (colb_ ^ ((r_&7)<<4))); \
            }                                                                 \
            _Pragma("unroll")                                                 \
            for (int nf_ = 0; nf_ < 4; ++nf_) {                               \
                const int rr_ = nf_*16 + (lane&15);                           \
                b_[nf_] = *(const short8v*)((char*)&Bsw[BUF][0] + rr_*128 + (colb_ ^ (((rr_>>1)&7)<<4))); \
            }                                                                 \
            _Pragma("unroll")                                                 \
            for (int mf_ = 0; mf_ < 2; ++mf_)                                 \
                _Pragma("unroll")                                             \
                for (int nf_ = 0; nf_ < 4; ++nf_)                             \
                    acc[mf_][nf_] = __builtin_amdgcn_mfma_f32_16x16x32_bf16(a_[mf_], b_[nf_], acc[mf_][nf_], 0, 0, 0); \
        }                                                                     \
    } while(0)

    #define FENCE() asm volatile("" ::: "memory")
    #define BARN(NSTR) do {                                                   \
        asm volatile("s_waitcnt vmcnt(" NSTR ") lgkmcnt(0)" ::: "memory");    \
        __builtin_amdgcn_sched_barrier(0);                                    \
        __builtin_amdgcn_s_barrier(); } while(0)

    // ---- prologue: A(0) gloads FIRST (oldest in FIFO), then X(0), X(1)
    A_GLOAD(0, 0);
    FENCE();
    X_LOAD(xrA, mvA0, mvA1, 0);
    X_LOAD(xrB, mvB0, mvB1, 64);
    WRITE_B(xrA, mvA0, mvA1, 0);   // waits X(0) -> implies A(0) done (older)
    BARN("10");                     // X(1)'s 10 loads remain in flight

    // ---- steady loop: t = 0..29
    // STEP(t even): A(t+1)->buf1, X(t+2)->setA, compute buf0, write X(t+1)=setB->buf1
    #define STEP_EVEN(T) do {                                                 \
        A_GLOAD(1, ((T)+1)*64);                                               \
        FENCE();                                                              \
        X_LOAD(xrA, mvA0, mvA1, ((T)+2)*64);                                  \
        COMPUTE(0);                                                           \
        __builtin_amdgcn_sched_barrier(0);                                    \
        WRITE_B(xrB, mvB0, mvB1, 1);                                          \
        BARN("10");                                                           \
    } while(0)
    #define STEP_ODD(T) do {                                                  \
        A_GLOAD(0, ((T)+1)*64);                                               \
        FENCE();                                                              \
        X_LOAD(xrB, mvB0, mvB1, ((T)+2)*64);                                  \
        COMPUTE(1);                                                           \
        __builtin_amdgcn_sched_barrier(0);                                    \
        WRITE_B(xrA, mvA0, mvA1, 0);                                          \
        BARN("10");                                                           \
    } while(0)

    for (int tb = 0; tb < 30; tb += 2) {
        STEP_EVEN(tb);
        STEP_ODD(tb+1);
    }
    // ---- tail: t=30 (compute buf0, stage A(31), write X(31)=setB), t=31
    A_GLOAD(1, 31*64);
    FENCE();
    COMPUTE(0);
    __builtin_amdgcn_sched_barrier(0);
    WRITE_B(xrB, mvB0, mvB1, 1);
    BARN("0");
    COMPUTE(1);

    // epilogue: col = lane&15 (d), row = (lane>>4)*4 + r (m)
    #pragma unroll
    for (int mf = 0; mf < 2; ++mf)
        #pragma unroll
        for (int nf = 0; nf < 4; ++nf)
            #pragma unroll
            for (int r = 0; r < 4; ++r) {
                const int m = wv*32 + mf*16 + (lane>>4)*4 + r;
                const int d = nf*16 + (lane&15);
                Y[(size_t)m*D_ + d] = acc[mf][nf][r];
            }
    #undef A_GLOAD
    #undef X_LOAD
    #undef WRITE_B
    #undef COMPUTE
    #undef FENCE
    #undef BARN
    #undef STEP_EVEN
    #undef STEP_ODD
}

// ---------------- K2: fused energy -> softmax -> ctx (fp32), bf16 transposed out
__global__ __launch_bounds__(256)
void attn_kernel(const float* __restrict__ Qd, const float* __restrict__ Kd,
                 const float* __restrict__ Vd, unsigned short* __restrict__ CtxT)
{
    __shared__ __align__(16) float S[M_][D_];    // 64 KB
    const int mt = blockIdx.x;
    const int bh = blockIdx.y;
    const float* qd = Qd + (size_t)bh * M_ * D_;
    const float* kd = Kd + (size_t)bh * M_ * D_;
    const float* vd = Vd + (size_t)bh * M_ * D_;

    const int tid = threadIdx.x;
    const int r = tid >> 2, sub = tid & 3;
    const int m = mt * 64 + r;

    float q[64];
    #pragma unroll
    for (int g = 0; g < 16; ++g) {
        const float4 t = ld4(qd + (size_t)m * D_ + g*4);
        q[4*g+0] = t.x; q[4*g+1] = t.y; q[4*g+2] = t.z; q[4*g+3] = t.w;
    }

    #pragma unroll
    for (int it = 0; it < 16; ++it) {
        const int i = tid + it*256;
        const int k = i >> 4, g = i & 15;
        const float4 t = ld4(kd + (size_t)i * 4);
        *(float4*)(&S[k][(g ^ (k & 3)) * 4]) = t;
    }
    __syncthreads();

    float e[64];
    #pragma unroll
    for (int kk = 0; kk < 64; ++kk) {
        const int k = kk*4 + sub;
        float acc = 0.f;
        #pragma unroll
        for (int g = 0; g < 16; ++g) {
            const float4 t = ld4(&S[k][(g ^ sub) * 4]);
            acc = fmaf(q[4*g+0], t.x, acc);
            acc = fmaf(q[4*g+1], t.y, acc);
            acc = fmaf(q[4*g+2], t.z, acc);
            acc = fmaf(q[4*g+3], t.w, acc);
        }
        e[kk] = acc;
    }

    float mx = e[0];
    #pragma unroll
    for (int kk = 1; kk < 64; ++kk) mx = fmaxf(mx, e[kk]);
    mx = fmaxf(mx, __shfl_xor(mx, 1));
    mx = fmaxf(mx, __shfl_xor(mx, 2));
    float sum = 0.f;
    #pragma unroll
    for (int kk = 0; kk < 64; ++kk) { e[kk] = __expf(e[kk] - mx); sum += e[kk]; }
    sum += __shfl_xor(sum, 1);
    sum += __shfl_xor(sum, 2);
    const float inv = 1.0f / sum;

    __syncthreads();
    #pragma unroll
    for (int it = 0; it < 16; ++it) {
        const int i = tid + it*256;
        const int k = i >> 4, g = i & 15;
        const float4 t = ld4(vd + (size_t)i * 4);
        *(float4*)(&S[k][(g ^ (k & 3)) * 4]) = t;
    }
    __syncthreads();

    float c[64] = {};
    #pragma unroll
    for (int kk = 0; kk < 64; ++kk) {
        const int k = kk*4 + sub;
        const float a = e[kk];
        #pragma unroll
        for (int g = 0; g < 16; ++g) {
            const float4 t = ld4(&S[k][(g ^ sub) * 4]);
            c[4*g+0] = fmaf(a, t.x, c[4*g+0]);
            c[4*g+1] = fmaf(a, t.y, c[4*g+1]);
            c[4*g+2] = fmaf(a, t.z, c[4*g+2]);
            c[4*g+3] = fmaf(a, t.w, c[4*g+3]);
        }
    }
    #pragma unroll
    for (int d = 0; d < 64; ++d) {
        c[d] += __shfl_xor(c[d], 1);
        c[d] += __shfl_xor(c[d], 2);
    }

    __syncthreads();
    unsigned short* T = (unsigned short*)&S[0][0];   // [64 d][72 m] ushorts
    #pragma unroll
    for (int g = 0; g < 16; ++g) {
        const int d = sub*16 + g;
        T[d*72 + r] = f2bf(c[d]*inv);
    }
    __syncthreads();
    const int d2 = tid >> 2, mg = tid & 3;
    uint4 w0 = *(uint4*)&T[d2*72 + mg*16];
    uint4 w1 = *(uint4*)&T[d2*72 + mg*16 + 8];
    unsigned short* dst = CtxT + (size_t)bh*D_*M_ + (size_t)d2*M_ + mt*64 + mg*16;
    *(uint4*)dst = w0; *(uint4*)(dst+8) = w1;
}

// ---------------- K3: x = DctT @ ctx_t^T, MFMA bf16 ------------------------
__global__ __launch_bounds__(128, 2)
void gemm_out(const unsigned short* __restrict__ DctT, const unsigned short* __restrict__ CtxT,
              float* __restrict__ Out)
{
    __shared__ __align__(16) unsigned short Asw[128*64];
    __shared__ __align__(16) unsigned short Bsw[64*64];
    const int nt = blockIdx.x, bh = blockIdx.y;
    const int n0 = nt*128;
    const unsigned short* ct = CtxT + (size_t)bh*D_*M_;
    float* out = Out + (size_t)bh*N_*D_;
    const int tid = threadIdx.x;
    const int lane = tid & 63, wave = tid >> 6;

    f32x4 acc[4][4];
    #pragma unroll
    for (int i = 0; i < 4; ++i)
        #pragma unroll
        for (int j = 0; j < 4; ++j) { acc[i][j].x=0.f; acc[i][j].y=0.f; acc[i][j].z=0.f; acc[i][j].w=0.f; }

    for (int step = 0; step < 4; ++step) {
        const int k0 = step*64;
        if (step) __syncthreads();
        const int ch = tid & 7;
        #pragma unroll
        for (int rr = 0; rr < 8; ++rr) {
            const int r = (tid>>3) + rr*16;
            const uint4 v = *(const uint4*)(DctT + (size_t)(n0+r)*M_ + k0 + ch*8);
            *(uint4*)((char*)Asw + r*128 + ((ch*16) ^ ((r&7)<<4))) = v;
        }
        #pragma unroll
        for (int rr = 0; rr < 4; ++rr) {
            const int d = (tid>>3) + rr*16;
            const uint4 v = *(const uint4*)(ct + (size_t)d*M_ + k0 + ch*8);
            *(uint4*)((char*)Bsw + d*128 + ((ch*16) ^ (((d>>1)&7)<<4))) = v;
        }
        __syncthreads();
        #pragma unroll
        for (int kh = 0; kh < 2; ++kh) {
            const int colb = kh*64 + (lane>>4)*16;
            short8v a[4], bb[4];
            #pragma unroll
            for (int mf = 0; mf < 4; ++mf) {
                const int r = wave*64 + mf*16 + (lane&15);
                a[mf] = *(const short8v*)((char*)Asw + r*128 + (colb ^ ((r&7)<<4)));
            }
            #pragma unroll
            for (int nf = 0; nf < 4; ++nf) {
                const int r = nf*16 + (lane&15);
                bb[nf] = *(const short8v*)((char*)Bsw + r*128 + (colb ^ (((r>>1)&7)<<4)));
            }
            #pragma unroll
            for (int mf = 0; mf < 4; ++mf)
                #pragma unroll
                for (int nf = 0; nf < 4; ++nf)
                    acc[mf][nf] = __builtin_amdgcn_mfma_f32_16x16x32_bf16(a[mf], bb[nf], acc[mf][nf], 0, 0, 0);
        }
    }
    #pragma unroll
    for (int mf = 0; mf < 4; ++mf)
        #pragma unroll
        for (int nf = 0; nf < 4; ++nf)
            #pragma unroll
            for (int r = 0; r < 4; ++r) {
                const int n = n0 + wave*64 + mf*16 + (lane>>4)*4 + r;
                const int d = nf*16 + (lane&15);
                out[(size_t)n*D_ + d] = acc[mf][nf][r];
            }
}

extern "C" void kernel_launch(void* const* d_in, const int* in_sizes, int n_in,
                              void* d_out, int out_size, void* d_ws, size_t ws_size,
                              hipStream_t stream) {
    const float* Q    = (const float*)d_in[0];
    const float* K    = (const float*)d_in[1];
    const float* V    = (const float*)d_in[2];
    const float* mask = (const float*)d_in[3];
    const float* Dct  = (const float*)d_in[4];
    float* out = (float*)d_out;

    const size_t per = (size_t)BH_ * M_ * D_;          // 1,572,864
    float* wsf = (float*)d_ws;
    float* Qd = wsf;
    float* Kd = Qd + per;
    float* Vd = Kd + per;
    unsigned short* CtxT = (unsigned short*)(Vd + per);  // per ushorts
    unsigned short* DctB = CtxT + per;                   // 524288
    unsigned short* DctT = DctB + (size_t)M_ * N_;       // 524288

    dct_prep_kernel<<<dim3(N_/64, M_/64), 256, 0, stream>>>(Dct, DctB, DctT);
    gemm_qkv<<<dim3(3*BH_), 512, 0, stream>>>(Q, K, V, mask, DctB, Qd, Kd, Vd);
    attn_kernel<<<dim3(M_/64, BH_), 256, 0, stream>>>(Qd, Kd, Vd, CtxT);
    gemm_out<<<dim3(N_/128, BH_), 128, 0, stream>>>(DctT, CtxT, out);
}

// Round 8
// 131.619 us; speedup vs baseline: 1.2223x; 1.0108x over previous
//
#include <hip/hip_runtime.h>
#include <hip/hip_bf16.h>
#include <cstddef>

#define B_ 8
#define H_ 12
#define N_ 2048
#define D_ 64
#define M_ 256
#define BH_ (B_*H_)

typedef __attribute__((ext_vector_type(8))) short short8v;
typedef __attribute__((ext_vector_type(4))) float f32x4;

static __device__ __forceinline__ float4 ld4(const float* p){ return *(const float4*)p; }

static __device__ __forceinline__ unsigned short f2bf(float x){
    union { float f; unsigned int u; } v; v.f = x;
    unsigned int r = v.u + 0x7FFFu + ((v.u >> 16) & 1u);
    return (unsigned short)(r >> 16);
}
static __device__ __forceinline__ unsigned int pack2(float a, float b){
    return (unsigned int)f2bf(a) | ((unsigned int)f2bf(b) << 16);
}

// ---------------- K0: Dct fp32 -> DctA (MFMA frag-linear bf16) + DctT bf16 ----
// DctA layout: frag (fm, fk) covers rows [16fm,16fm+16) x k [32fk, 32fk+32).
// Element (lane, j): row = 16fm + (lane&15), k = 32fk + (lane>>4)*8 + j.
// Linear: DctA[((fm*64 + fk)*64 + lane)*8 + j]  -> a wave A-frag load is one
// coalesced 1 KB global_load_dwordx4. 1 MB total, L2-resident, shared by all.
__global__ __launch_bounds__(256)
void dct_prep_kernel(const float* __restrict__ Dct, unsigned short* __restrict__ DctA,
                     unsigned short* __restrict__ DctT)
{
    __shared__ __align__(16) unsigned short T[64*72];
    const int n0 = blockIdx.x * 64, m0 = blockIdx.y * 64;
    const int tid = threadIdx.x;
    const int mrow = tid >> 2, ng = tid & 3;
    const int m = m0 + mrow;
    unsigned short h[16];
    #pragma unroll
    for (int j = 0; j < 4; ++j) {
        const float4 t = ld4(Dct + (size_t)m*N_ + n0 + ng*16 + j*4);
        h[4*j+0]=f2bf(t.x); h[4*j+1]=f2bf(t.y); h[4*j+2]=f2bf(t.z); h[4*j+3]=f2bf(t.w);
    }
    unsigned int w[8];
    #pragma unroll
    for (int j = 0; j < 8; ++j) w[j] = (unsigned int)h[2*j] | ((unsigned int)h[2*j+1]<<16);
    // frag-linear stores: two halves s=0,1 (8 shorts each)
    const int fm = m >> 4;
    #pragma unroll
    for (int s = 0; s < 2; ++s) {
        const int u = 2*ng + s;                   // 0..7
        const int fk = (n0 >> 5) + (u >> 2);
        const int lane = (m & 15) + (u & 3) * 16;
        unsigned short* dst = DctA + ((size_t)(fm*64 + fk)*64 + lane)*8;
        *(uint4*)dst = *(uint4*)&w[s*4];
    }
    #pragma unroll
    for (int j = 0; j < 16; ++j) T[(ng*16+j)*72 + mrow] = h[j];
    __syncthreads();
    const int n = tid >> 2, mg = tid & 3;
    uint4 a  = *(uint4*)&T[n*72 + mg*16];
    uint4 b2 = *(uint4*)&T[n*72 + mg*16 + 8];
    unsigned short* dt = DctT + (size_t)(n0+n)*M_ + m0 + mg*16;
    *(uint4*)dt = a; *(uint4*)(dt+8) = b2;
}

// ---------------- K1: Qd/Kd/Vd = Dct @ (scaled/masked X), MFMA bf16 ----------
// 288 blocks = (bh,tz), 512 threads (8 waves). Full 256m x 64d per block; X read
// exactly once. BK=64, 32 steps. A-frags: coalesced register loads from the
// frag-linear DctA (L2-hot), depth-2 prefetch — NO LDS for A. B (X) reg-staged
// depth-2 then ds_write (16 KB dbuf only). Barrier = lgkmcnt(0) + s_barrier;
// no vmcnt drain anywhere — global loads stay in flight across barriers.
__global__ __launch_bounds__(512, 4)
void gemm_qkv(const float* __restrict__ Q, const float* __restrict__ K,
              const float* __restrict__ V, const float* __restrict__ mask,
              const unsigned short* __restrict__ DctA,
              float* __restrict__ Qd, float* __restrict__ Kd, float* __restrict__ Vd)
{
    __shared__ __align__(16) unsigned short Bsw[2][64*64];   // 2 x 8 KB, row 128 B
    const int wg = blockIdx.x;
    const int bh = wg % BH_;
    const int tz = wg / BH_;
    const int b  = bh / H_;
    const float scale = 0.35355339059327373f;
    const float* X; float* Y; float smul; int um;
    if (tz==0)      { X=Q; Y=Qd; smul=scale; um=0; }
    else if (tz==1) { X=K; Y=Kd; smul=scale; um=1; }
    else            { X=V; Y=Vd; smul=1.0f;  um=1; }
    X += (size_t)bh*N_*D_;
    Y += (size_t)bh*M_*D_;

    const int tid  = threadIdx.x;
    const int lane = tid & 63, wv = tid >> 6;   // 8 waves; wave owns m rows [32wv,32wv+32)
    // A frag base: frag (fm = 2wv+mf, fk), element = abase + (mf*64 + fk)*512
    const unsigned short* abase = DctA + (size_t)wv*65536 + (size_t)lane*8;
    // B staging: wave wv covers k rows [8wv,8wv+8), lane covers d = lane
    const float* xcol = X + lane;
    const int bswz = ((lane>>1)&7)<<4;

    f32x4 acc[2][4];
    #pragma unroll
    for (int i = 0; i < 2; ++i)
        #pragma unroll
        for (int j = 0; j < 4; ++j) { acc[i][j].x=0.f; acc[i][j].y=0.f; acc[i][j].z=0.f; acc[i][j].w=0.f; }

    short8v pa[2][2], pb[2][2];   // A-frag prefetch sets [mf][kh]
    float  xrA[8], xrB[8];
    float4 mvA0, mvA1, mvB0, mvB1;

    #define A_LOAD(P, T) do {                                                 \
        _Pragma("unroll")                                                     \
        for (int mf_ = 0; mf_ < 2; ++mf_)                                     \
            _Pragma("unroll")                                                 \
            for (int kh_ = 0; kh_ < 2; ++kh_)                                 \
                P[mf_][kh_] = *(const short8v*)(abase + (size_t)(mf_*64 + 2*(T)+kh_)*512); \
    } while(0)

    #define X_LOAD(XR, M0, M1, K0) do {                                      \
        const float* xp_ = xcol + (size_t)((K0) + wv*8) * D_;                 \
        _Pragma("unroll")                                                     \
        for (int i_ = 0; i_ < 8; ++i_) XR[i_] = xp_[(size_t)i_*D_];           \
        const float* mp_ = mask + (size_t)b*N_ + (K0) + wv*8;                 \
        M0 = ld4(mp_); M1 = ld4(mp_ + 4);                                     \
    } while(0)

    #define WRITE_B(XR, M0, M1, BUF) do {                                    \
        float f_[8];                                                          \
        f_[0] = um ? smul*M0.x : smul;  f_[1] = um ? smul*M0.y : smul;        \
        f_[2] = um ? smul*M0.z : smul;  f_[3] = um ? smul*M0.w : smul;        \
        f_[4] = um ? smul*M1.x : smul;  f_[5] = um ? smul*M1.y : smul;        \
        f_[6] = um ? smul*M1.z : smul;  f_[7] = um ? smul*M1.w : smul;        \
        uint4 w_;                                                             \
        w_.x = pack2(XR[0]*f_[0], XR[1]*f_[1]);                               \
        w_.y = pack2(XR[2]*f_[2], XR[3]*f_[3]);                               \
        w_.z = pack2(XR[4]*f_[4], XR[5]*f_[5]);                               \
        w_.w = pack2(XR[6]*f_[6], XR[7]*f_[7]);                               \
        *(uint4*)((char*)&Bsw[BUF][0] + lane*128 + ((wv*16) ^ bswz)) = w_;    \
    } while(0)

    #define COMPUTE(BUF, P) do {                                              \
        _Pragma("unroll")                                                     \
        for (int kh_ = 0; kh_ < 2; ++kh_) {                                   \
            const int colb_ = kh_*64 + (lane>>4)*16;                          \
            short8v b_[4];                                                    \
            _Pragma("unroll")                                                 \
            for (int nf_ = 0; nf_ < 4; ++nf_) {                               \
                const int rr_ = nf_*16 + (lane&15);                           \
                b_[nf_] = *(const short8v*)((char*)&Bsw[BUF][0] + rr_*128 + (colb_ ^ (((rr_>>1)&7)<<4))); \
            }                                                                 \
            _Pragma("unroll")                                                 \
            for (int mf_ = 0; mf_ < 2; ++mf_)                                 \
                _Pragma("unroll")                                             \
                for (int nf_ = 0; nf_ < 4; ++nf_)                             \
                    acc[mf_][nf_] = __builtin_amdgcn_mfma_f32_16x16x32_bf16(P[mf_][kh_], b_[nf_], acc[mf_][nf_], 0, 0, 0); \
        }                                                                     \
    } while(0)

    #define BARJ() do { asm volatile("s_waitcnt lgkmcnt(0)" ::: "memory");    \
                        __builtin_amdgcn_sched_barrier(0);                    \
                        __builtin_amdgcn_s_barrier(); } while(0)

    // ---- prologue
    A_LOAD(pa, 0);
    X_LOAD(xrA, mvA0, mvA1, 0);
    X_LOAD(xrB, mvB0, mvB1, 64);
    WRITE_B(xrA, mvA0, mvA1, 0);
    BARJ();

    // ---- steady loop t = 0..29 (15 pairs)
    #define STEP_EVEN(T) do {                                                 \
        A_LOAD(pb, (T)+1);                                                    \
        X_LOAD(xrA, mvA0, mvA1, ((T)+2)*64);                                  \
        COMPUTE(0, pa);                                                       \
        __builtin_amdgcn_sched_barrier(0);                                    \
        WRITE_B(xrB, mvB0, mvB1, 1);                                          \
        BARJ();                                                               \
    } while(0)
    #define STEP_ODD(T) do {                                                  \
        A_LOAD(pa, (T)+1);                                                    \
        X_LOAD(xrB, mvB0, mvB1, ((T)+2)*64);                                  \
        COMPUTE(1, pb);                                                       \
        __builtin_amdgcn_sched_barrier(0);                                    \
        WRITE_B(xrA, mvA0, mvA1, 0);                                          \
        BARJ();                                                               \
    } while(0)

    for (int tb = 0; tb < 30; tb += 2) {
        STEP_EVEN(tb);
        STEP_ODD(tb+1);
    }
    // ---- tail: t=30, t=31
    A_LOAD(pb, 31);
    COMPUTE(0, pa);
    __builtin_amdgcn_sched_barrier(0);
    WRITE_B(xrB, mvB0, mvB1, 1);
    BARJ();
    COMPUTE(1, pb);

    // epilogue: col = lane&15 (d), row = (lane>>4)*4 + r (m)
    #pragma unroll
    for (int mf = 0; mf < 2; ++mf)
        #pragma unroll
        for (int nf = 0; nf < 4; ++nf)
            #pragma unroll
            for (int r = 0; r < 4; ++r) {
                const int m = wv*32 + mf*16 + (lane>>4)*4 + r;
                const int d = nf*16 + (lane&15);
                Y[(size_t)m*D_ + d] = acc[mf][nf][r];
            }
    #undef A_LOAD
    #undef X_LOAD
    #undef WRITE_B
    #undef COMPUTE
    #undef BARJ
    #undef STEP_EVEN
    #undef STEP_ODD
}

// ---------------- K2: fused energy -> softmax -> ctx (fp32), bf16 transposed out
__global__ __launch_bounds__(256)
void attn_kernel(const float* __restrict__ Qd, const float* __restrict__ Kd,
                 const float* __restrict__ Vd, unsigned short* __restrict__ CtxT)
{
    __shared__ __align__(16) float S[M_][D_];    // 64 KB
    const int mt = blockIdx.x;
    const int bh = blockIdx.y;
    const float* qd = Qd + (size_t)bh * M_ * D_;
    const float* kd = Kd + (size_t)bh * M_ * D_;
    const float* vd = Vd + (size_t)bh * M_ * D_;

    const int tid = threadIdx.x;
    const int r = tid >> 2, sub = tid & 3;
    const int m = mt * 64 + r;

    float q[64];
    #pragma unroll
    for (int g = 0; g < 16; ++g) {
        const float4 t = ld4(qd + (size_t)m * D_ + g*4);
        q[4*g+0] = t.x; q[4*g+1] = t.y; q[4*g+2] = t.z; q[4*g+3] = t.w;
    }

    #pragma unroll
    for (int it = 0; it < 16; ++it) {
        const int i = tid + it*256;
        const int k = i >> 4, g = i & 15;
        const float4 t = ld4(kd + (size_t)i * 4);
        *(float4*)(&S[k][(g ^ (k & 3)) * 4]) = t;
    }
    __syncthreads();

    float e[64];
    #pragma unroll
    for (int kk = 0; kk < 64; ++kk) {
        const int k = kk*4 + sub;
        float acc = 0.f;
        #pragma unroll
        for (int g = 0; g < 16; ++g) {
            const float4 t = ld4(&S[k][(g ^ sub) * 4]);
            acc = fmaf(q[4*g+0], t.x, acc);
            acc = fmaf(q[4*g+1], t.y, acc);
            acc = fmaf(q[4*g+2], t.z, acc);
            acc = fmaf(q[4*g+3], t.w, acc);
        }
        e[kk] = acc;
    }

    float mx = e[0];
    #pragma unroll
    for (int kk = 1; kk < 64; ++kk) mx = fmaxf(mx, e[kk]);
    mx = fmaxf(mx, __shfl_xor(mx, 1));
    mx = fmaxf(mx, __shfl_xor(mx, 2));
    float sum = 0.f;
    #pragma unroll
    for (int kk = 0; kk < 64; ++kk) { e[kk] = __expf(e[kk] - mx); sum += e[kk]; }
    sum += __shfl_xor(sum, 1);
    sum += __shfl_xor(sum, 2);
    const float inv = 1.0f / sum;

    __syncthreads();
    #pragma unroll
    for (int it = 0; it < 16; ++it) {
        const int i = tid + it*256;
        const int k = i >> 4, g = i & 15;
        const float4 t = ld4(vd + (size_t)i * 4);
        *(float4*)(&S[k][(g ^ (k & 3)) * 4]) = t;
    }
    __syncthreads();

    float c[64] = {};
    #pragma unroll
    for (int kk = 0; kk < 64; ++kk) {
        const int k = kk*4 + sub;
        const float a = e[kk];
        #pragma unroll
        for (int g = 0; g < 16; ++g) {
            const float4 t = ld4(&S[k][(g ^ sub) * 4]);
            c[4*g+0] = fmaf(a, t.x, c[4*g+0]);
            c[4*g+1] = fmaf(a, t.y, c[4*g+1]);
            c[4*g+2] = fmaf(a, t.z, c[4*g+2]);
            c[4*g+3] = fmaf(a, t.w, c[4*g+3]);
        }
    }
    #pragma unroll
    for (int d = 0; d < 64; ++d) {
        c[d] += __shfl_xor(c[d], 1);
        c[d] += __shfl_xor(c[d], 2);
    }

    __syncthreads();
    unsigned short* T = (unsigned short*)&S[0][0];   // [64 d][72 m] ushorts
    #pragma unroll
    for (int g = 0; g < 16; ++g) {
        const int d = sub*16 + g;
        T[d*72 + r] = f2bf(c[d]*inv);
    }
    __syncthreads();
    const int d2 = tid >> 2, mg = tid & 3;
    uint4 w0 = *(uint4*)&T[d2*72 + mg*16];
    uint4 w1 = *(uint4*)&T[d2*72 + mg*16 + 8];
    unsigned short* dst = CtxT + (size_t)bh*D_*M_ + (size_t)d2*M_ + mt*64 + mg*16;
    *(uint4*)dst = w0; *(uint4*)(dst+8) = w1;
}

// ---------------- K3: x = DctT @ ctx_t^T, MFMA bf16 ------------------------
__global__ __launch_bounds__(128, 2)
void gemm_out(const unsigned short* __restrict__ DctT, const unsigned short* __restrict__ CtxT,
              float* __restrict__ Out)
{
    __shared__ __align__(16) unsigned short Asw[128*64];
    __shared__ __align__(16) unsigned short Bsw[64*64];
    const int nt = blockIdx.x, bh = blockIdx.y;
    const int n0 = nt*128;
    const unsigned short* ct = CtxT + (size_t)bh*D_*M_;
    float* out = Out + (size_t)bh*N_*D_;
    const int tid = threadIdx.x;
    const int lane = tid & 63, wave = tid >> 6;

    f32x4 acc[4][4];
    #pragma unroll
    for (int i = 0; i < 4; ++i)
        #pragma unroll
        for (int j = 0; j < 4; ++j) { acc[i][j].x=0.f; acc[i][j].y=0.f; acc[i][j].z=0.f; acc[i][j].w=0.f; }

    for (int step = 0; step < 4; ++step) {
        const int k0 = step*64;
        if (step) __syncthreads();
        const int ch = tid & 7;
        #pragma unroll
        for (int rr = 0; rr < 8; ++rr) {
            const int r = (tid>>3) + rr*16;
            const uint4 v = *(const uint4*)(DctT + (size_t)(n0+r)*M_ + k0 + ch*8);
            *(uint4*)((char*)Asw + r*128 + ((ch*16) ^ ((r&7)<<4))) = v;
        }
        #pragma unroll
        for (int rr = 0; rr < 4; ++rr) {
            const int d = (tid>>3) + rr*16;
            const uint4 v = *(const uint4*)(ct + (size_t)d*M_ + k0 + ch*8);
            *(uint4*)((char*)Bsw + d*128 + ((ch*16) ^ (((d>>1)&7)<<4))) = v;
        }
        __syncthreads();
        #pragma unroll
        for (int kh = 0; kh < 2; ++kh) {
            const int colb = kh*64 + (lane>>4)*16;
            short8v a[4], bb[4];
            #pragma unroll
            for (int mf = 0; mf < 4; ++mf) {
                const int r = wave*64 + mf*16 + (lane&15);
                a[mf] = *(const short8v*)((char*)Asw + r*128 + (colb ^ ((r&7)<<4)));
            }
            #pragma unroll
            for (int nf = 0; nf < 4; ++nf) {
                const int r = nf*16 + (lane&15);
                bb[nf] = *(const short8v*)((char*)Bsw + r*128 + (colb ^ (((r>>1)&7)<<4)));
            }
            #pragma unroll
            for (int mf = 0; mf < 4; ++mf)
                #pragma unroll
                for (int nf = 0; nf < 4; ++nf)
                    acc[mf][nf] = __builtin_amdgcn_mfma_f32_16x16x32_bf16(a[mf], bb[nf], acc[mf][nf], 0, 0, 0);
        }
    }
    #pragma unroll
    for (int mf = 0; mf < 4; ++mf)
        #pragma unroll
        for (int nf = 0; nf < 4; ++nf)
            #pragma unroll
            for (int r = 0; r < 4; ++r) {
                const int n = n0 + wave*64 + mf*16 + (lane>>4)*4 + r;
                const int d = nf*16 + (lane&15);
                out[(size_t)n*D_ + d] = acc[mf][nf][r];
            }
}

extern "C" void kernel_launch(void* const* d_in, const int* in_sizes, int n_in,
                              void* d_out, int out_size, void* d_ws, size_t ws_size,
                              hipStream_t stream) {
    const float* Q    = (const float*)d_in[0];
    const float* K    = (const float*)d_in[1];
    const float* V    = (const float*)d_in[2];
    const float* mask = (const float*)d_in[3];
    const float* Dct  = (const float*)d_in[4];
    float* out = (float*)d_out;

    const size_t per = (size_t)BH_ * M_ * D_;          // 1,572,864
    float* wsf = (float*)d_ws;
    float* Qd = wsf;
    float* Kd = Qd + per;
    float* Vd = Kd + per;
    unsigned short* CtxT = (unsigned short*)(Vd + per);  // per ushorts
    unsigned short* DctA = CtxT + per;                   // 524288 (frag-linear)
    unsigned short* DctT = DctA + (size_t)M_ * N_;       // 524288

    dct_prep_kernel<<<dim3(N_/64, M_/64), 256, 0, stream>>>(Dct, DctA, DctT);
    gemm_qkv<<<dim3(3*BH_), 512, 0, stream>>>(Q, K, V, mask, DctA, Qd, Kd, Vd);
    attn_kernel<<<dim3(M_/64, BH_), 256, 0, stream>>>(Qd, Kd, Vd, CtxT);
    gemm_out<<<dim3(N_/128, BH_), 128, 0, stream>>>(DctT, CtxT, out);
}

// Round 9
// 125.795 us; speedup vs baseline: 1.2789x; 1.0463x over previous
//
#include <hip/hip_runtime.h>
#include <hip/hip_bf16.h>
#include <cstddef>

#define B_ 8
#define H_ 12
#define N_ 2048
#define D_ 64
#define M_ 256
#define BH_ (B_*H_)

typedef __attribute__((ext_vector_type(8))) short short8v;
typedef __attribute__((ext_vector_type(4))) float f32x4;

static __device__ __forceinline__ float4 ld4(const float* p){ return *(const float4*)p; }

static __device__ __forceinline__ unsigned short f2bf(float x){
    union { float f; unsigned int u; } v; v.f = x;
    unsigned int r = v.u + 0x7FFFu + ((v.u >> 16) & 1u);
    return (unsigned short)(r >> 16);
}
static __device__ __forceinline__ unsigned int pack2(float a, float b){
    return (unsigned int)f2bf(a) | ((unsigned int)f2bf(b) << 16);
}

// ---------------- K0: Dct fp32 -> DctA (MFMA frag-linear bf16) + DctT bf16 ----
// DctA layout: frag (fm, fk) covers rows [16fm,16fm+16) x k [32fk, 32fk+32).
// Element (lane, j): row = 16fm + (lane&15), k = 32fk + (lane>>4)*8 + j.
// Linear: DctA[((fm*64 + fk)*64 + lane)*8 + j]  -> a wave A-frag load is one
// coalesced 1 KB global_load_dwordx4. 1 MB total, L2-resident, shared by all.
__global__ __launch_bounds__(256)
void dct_prep_kernel(const float* __restrict__ Dct, unsigned short* __restrict__ DctA,
                     unsigned short* __restrict__ DctT)
{
    __shared__ __align__(16) unsigned short T[64*72];
    const int n0 = blockIdx.x * 64, m0 = blockIdx.y * 64;
    const int tid = threadIdx.x;
    const int mrow = tid >> 2, ng = tid & 3;
    const int m = m0 + mrow;
    unsigned short h[16];
    #pragma unroll
    for (int j = 0; j < 4; ++j) {
        const float4 t = ld4(Dct + (size_t)m*N_ + n0 + ng*16 + j*4);
        h[4*j+0]=f2bf(t.x); h[4*j+1]=f2bf(t.y); h[4*j+2]=f2bf(t.z); h[4*j+3]=f2bf(t.w);
    }
    unsigned int w[8];
    #pragma unroll
    for (int j = 0; j < 8; ++j) w[j] = (unsigned int)h[2*j] | ((unsigned int)h[2*j+1]<<16);
    const int fm = m >> 4;
    #pragma unroll
    for (int s = 0; s < 2; ++s) {
        const int u = 2*ng + s;                   // 0..7
        const int fk = (n0 >> 5) + (u >> 2);
        const int lane = (m & 15) + (u & 3) * 16;
        unsigned short* dst = DctA + ((size_t)(fm*64 + fk)*64 + lane)*8;
        *(uint4*)dst = *(uint4*)&w[s*4];
    }
    #pragma unroll
    for (int j = 0; j < 16; ++j) T[(ng*16+j)*72 + mrow] = h[j];
    __syncthreads();
    const int n = tid >> 2, mg = tid & 3;
    uint4 a  = *(uint4*)&T[n*72 + mg*16];
    uint4 b2 = *(uint4*)&T[n*72 + mg*16 + 8];
    unsigned short* dt = DctT + (size_t)(n0+n)*M_ + m0 + mg*16;
    *(uint4*)dt = a; *(uint4*)(dt+8) = b2;
}

// ---------------- K1: Qd/Kd/Vd = Dct @ (scaled/masked X), MFMA bf16 ----------
// 576 blocks = (panel=(bh,tz), half). 256 threads (4 waves). Each block: 128 m
// rows x 64 d, full K=2048 (BK=64, 32 steps). The two halves of a panel sit on
// the SAME XCD (id swizzle) so X is HBM-read once and L2-served for the twin.
// A-frags: depth-2 register loads from frag-linear DctA (L2-hot). B: depth-2
// reg-staged X -> row-XOR-swizzled LDS (16 KB dbuf). Barrier = lgkmcnt(0) only;
// global loads stay in flight across barriers (compiler inserts counted waits).
__global__ __launch_bounds__(256, 2)
void gemm_qkv(const float* __restrict__ Q, const float* __restrict__ K,
              const float* __restrict__ V, const float* __restrict__ mask,
              const unsigned short* __restrict__ DctA,
              float* __restrict__ Qd, float* __restrict__ Kd, float* __restrict__ Vd)
{
    __shared__ __align__(16) unsigned short Bsw[2][64*64];   // 2 x 8 KB, row 128 B
    const int wg = blockIdx.x;
    const int id = (wg & 7) * 72 + (wg >> 3);   // 576 = 8 XCD chunks x 72
    const int half  = id & 1;                   // halves of a panel adjacent -> same XCD
    const int panel = id >> 1;                  // 0..287
    const int bh = panel % BH_;
    const int tz = panel / BH_;
    const int b  = bh / H_;
    const float scale = 0.35355339059327373f;
    const float* X; float* Y; float smul; int um;
    if (tz==0)      { X=Q; Y=Qd; smul=scale; um=0; }
    else if (tz==1) { X=K; Y=Kd; smul=scale; um=1; }
    else            { X=V; Y=Vd; smul=1.0f;  um=1; }
    X += (size_t)bh*N_*D_;
    Y += (size_t)bh*M_*D_ + (size_t)half*128*D_;

    const int tid  = threadIdx.x;
    const int lane = tid & 63, wv = tid >> 6;   // 4 waves; wave owns m rows [32wv,32wv+32) of this half
    // A frag base: fm_global = half*8 + wv*2 + mf
    const unsigned short* abase = DctA + (size_t)(half*8 + wv*2)*32768 + (size_t)lane*8;
    // B staging: wave wv covers k rows [16wv,16wv+16), lane covers d = lane
    const float* xcol = X + lane;
    const int swz = (lane & 7) << 4;            // row-XOR applied to column chunk

    f32x4 acc[2][4];
    #pragma unroll
    for (int i = 0; i < 2; ++i)
        #pragma unroll
        for (int j = 0; j < 4; ++j) { acc[i][j].x=0.f; acc[i][j].y=0.f; acc[i][j].z=0.f; acc[i][j].w=0.f; }

    short8v pa[2][2], pb[2][2];   // A-frag prefetch sets [mf][kh]
    float  xrA[16], xrB[16];
    float4 mA0, mA1, mA2, mA3, mB0, mB1, mB2, mB3;

    #define A_LOAD(P, T) do {                                                 \
        _Pragma("unroll")                                                     \
        for (int mf_ = 0; mf_ < 2; ++mf_)                                     \
            _Pragma("unroll")                                                 \
            for (int kh_ = 0; kh_ < 2; ++kh_)                                 \
                P[mf_][kh_] = *(const short8v*)(abase + (size_t)(mf_*64 + 2*(T)+kh_)*512); \
    } while(0)

    #define X_LOAD(XR, M0, M1, M2, M3, K0) do {                               \
        const float* xp_ = xcol + (size_t)((K0) + wv*16) * D_;                \
        _Pragma("unroll")                                                     \
        for (int i_ = 0; i_ < 16; ++i_) XR[i_] = xp_[(size_t)i_*D_];          \
        const float* mp_ = mask + (size_t)b*N_ + (K0) + wv*16;                \
        M0 = ld4(mp_); M1 = ld4(mp_+4); M2 = ld4(mp_+8); M3 = ld4(mp_+12);    \
    } while(0)

    #define WRITE_B(XR, M0, M1, M2, M3, BUF) do {                             \
        float f_[16];                                                         \
        f_[ 0]=um?smul*M0.x:smul; f_[ 1]=um?smul*M0.y:smul;                   \
        f_[ 2]=um?smul*M0.z:smul; f_[ 3]=um?smul*M0.w:smul;                   \
        f_[ 4]=um?smul*M1.x:smul; f_[ 5]=um?smul*M1.y:smul;                   \
        f_[ 6]=um?smul*M1.z:smul; f_[ 7]=um?smul*M1.w:smul;                   \
        f_[ 8]=um?smul*M2.x:smul; f_[ 9]=um?smul*M2.y:smul;                   \
        f_[10]=um?smul*M2.z:smul; f_[11]=um?smul*M2.w:smul;                   \
        f_[12]=um?smul*M3.x:smul; f_[13]=um?smul*M3.y:smul;                   \
        f_[14]=um?smul*M3.z:smul; f_[15]=um?smul*M3.w:smul;                   \
        uint4 w0_, w1_;                                                       \
        w0_.x=pack2(XR[0]*f_[0],  XR[1]*f_[1]);                               \
        w0_.y=pack2(XR[2]*f_[2],  XR[3]*f_[3]);                               \
        w0_.z=pack2(XR[4]*f_[4],  XR[5]*f_[5]);                               \
        w0_.w=pack2(XR[6]*f_[6],  XR[7]*f_[7]);                               \
        w1_.x=pack2(XR[8]*f_[8],  XR[9]*f_[9]);                               \
        w1_.y=pack2(XR[10]*f_[10],XR[11]*f_[11]);                             \
        w1_.z=pack2(XR[12]*f_[12],XR[13]*f_[13]);                             \
        w1_.w=pack2(XR[14]*f_[14],XR[15]*f_[15]);                             \
        *(uint4*)((char*)&Bsw[BUF][0] + lane*128 + ((wv*32)      ^ swz)) = w0_; \
        *(uint4*)((char*)&Bsw[BUF][0] + lane*128 + ((wv*32 + 16) ^ swz)) = w1_; \
    } while(0)

    #define COMPUTE(BUF, P) do {                                              \
        _Pragma("unroll")                                                     \
        for (int kh_ = 0; kh_ < 2; ++kh_) {                                   \
            const int colb_ = kh_*64 + (lane>>4)*16;                          \
            short8v b_[4];                                                    \
            _Pragma("unroll")                                                 \
            for (int nf_ = 0; nf_ < 4; ++nf_) {                               \
                const int rr_ = nf_*16 + (lane&15);                           \
                b_[nf_] = *(const short8v*)((char*)&Bsw[BUF][0] + rr_*128 + (colb_ ^ ((rr_&7)<<4))); \
            }                                                                 \
            _Pragma("unroll")                                                 \
            for (int mf_ = 0; mf_ < 2; ++mf_)                                 \
                _Pragma("unroll")                                             \
                for (int nf_ = 0; nf_ < 4; ++nf_)                             \
                    acc[mf_][nf_] = __builtin_amdgcn_mfma_f32_16x16x32_bf16(P[mf_][kh_], b_[nf_], acc[mf_][nf_], 0, 0, 0); \
        }                                                                     \
    } while(0)

    #define BARJ() do { asm volatile("s_waitcnt lgkmcnt(0)" ::: "memory");    \
                        __builtin_amdgcn_sched_barrier(0);                    \
                        __builtin_amdgcn_s_barrier(); } while(0)

    // ---- prologue
    A_LOAD(pa, 0);
    X_LOAD(xrA, mA0, mA1, mA2, mA3, 0);
    X_LOAD(xrB, mB0, mB1, mB2, mB3, 64);
    WRITE_B(xrA, mA0, mA1, mA2, mA3, 0);
    BARJ();

    // ---- steady loop t = 0..29 (15 pairs)
    #define STEP_EVEN(T) do {                                                 \
        A_LOAD(pb, (T)+1);                                                    \
        X_LOAD(xrA, mA0, mA1, mA2, mA3, ((T)+2)*64);                          \
        COMPUTE(0, pa);                                                       \
        __builtin_amdgcn_sched_barrier(0);                                    \
        WRITE_B(xrB, mB0, mB1, mB2, mB3, 1);                                  \
        BARJ();                                                               \
    } while(0)
    #define STEP_ODD(T) do {                                                  \
        A_LOAD(pa, (T)+1);                                                    \
        X_LOAD(xrB, mB0, mB1, mB2, mB3, ((T)+2)*64);                          \
        COMPUTE(1, pb);                                                       \
        __builtin_amdgcn_sched_barrier(0);                                    \
        WRITE_B(xrA, mA0, mA1, mA2, mA3, 0);                                  \
        BARJ();                                                               \
    } while(0)

    for (int tb = 0; tb < 30; tb += 2) {
        STEP_EVEN(tb);
        STEP_ODD(tb+1);
    }
    // ---- tail: t=30, t=31
    A_LOAD(pb, 31);
    COMPUTE(0, pa);
    __builtin_amdgcn_sched_barrier(0);
    WRITE_B(xrB, mB0, mB1, mB2, mB3, 1);
    BARJ();
    COMPUTE(1, pb);

    // epilogue: col = lane&15 (d), row = (lane>>4)*4 + r (m)
    #pragma unroll
    for (int mf = 0; mf < 2; ++mf)
        #pragma unroll
        for (int nf = 0; nf < 4; ++nf)
            #pragma unroll
            for (int r = 0; r < 4; ++r) {
                const int m = wv*32 + mf*16 + (lane>>4)*4 + r;
                const int d = nf*16 + (lane&15);
                Y[(size_t)m*D_ + d] = acc[mf][nf][r];
            }
    #undef A_LOAD
    #undef X_LOAD
    #undef WRITE_B
    #undef COMPUTE
    #undef BARJ
    #undef STEP_EVEN
    #undef STEP_ODD
}

// ---------------- K2: fused energy -> softmax -> ctx (fp32), bf16 transposed out
__global__ __launch_bounds__(256)
void attn_kernel(const float* __restrict__ Qd, const float* __restrict__ Kd,
                 const float* __restrict__ Vd, unsigned short* __restrict__ CtxT)
{
    __shared__ __align__(16) float S[M_][D_];    // 64 KB
    const int mt = blockIdx.x;
    const int bh = blockIdx.y;
    const float* qd = Qd + (size_t)bh * M_ * D_;
    const float* kd = Kd + (size_t)bh * M_ * D_;
    const float* vd = Vd + (size_t)bh * M_ * D_;

    const int tid = threadIdx.x;
    const int r = tid >> 2, sub = tid & 3;
    const int m = mt * 64 + r;

    float q[64];
    #pragma unroll
    for (int g = 0; g < 16; ++g) {
        const float4 t = ld4(qd + (size_t)m * D_ + g*4);
        q[4*g+0] = t.x; q[4*g+1] = t.y; q[4*g+2] = t.z; q[4*g+3] = t.w;
    }

    #pragma unroll
    for (int it = 0; it < 16; ++it) {
        const int i = tid + it*256;
        const int k = i >> 4, g = i & 15;
        const float4 t = ld4(kd + (size_t)i * 4);
        *(float4*)(&S[k][(g ^ (k & 3)) * 4]) = t;
    }
    __syncthreads();

    float e[64];
    #pragma unroll
    for (int kk = 0; kk < 64; ++kk) {
        const int k = kk*4 + sub;
        float acc = 0.f;
        #pragma unroll
        for (int g = 0; g < 16; ++g) {
            const float4 t = ld4(&S[k][(g ^ sub) * 4]);
            acc = fmaf(q[4*g+0], t.x, acc);
            acc = fmaf(q[4*g+1], t.y, acc);
            acc = fmaf(q[4*g+2], t.z, acc);
            acc = fmaf(q[4*g+3], t.w, acc);
        }
        e[kk] = acc;
    }

    float mx = e[0];
    #pragma unroll
    for (int kk = 1; kk < 64; ++kk) mx = fmaxf(mx, e[kk]);
    mx = fmaxf(mx, __shfl_xor(mx, 1));
    mx = fmaxf(mx, __shfl_xor(mx, 2));
    float sum = 0.f;
    #pragma unroll
    for (int kk = 0; kk < 64; ++kk) { e[kk] = __expf(e[kk] - mx); sum += e[kk]; }
    sum += __shfl_xor(sum, 1);
    sum += __shfl_xor(sum, 2);
    const float inv = 1.0f / sum;

    __syncthreads();
    #pragma unroll
    for (int it = 0; it < 16; ++it) {
        const int i = tid + it*256;
        const int k = i >> 4, g = i & 15;
        const float4 t = ld4(vd + (size_t)i * 4);
        *(float4*)(&S[k][(g ^ (k & 3)) * 4]) = t;
    }
    __syncthreads();

    float c[64] = {};
    #pragma unroll
    for (int kk = 0; kk < 64; ++kk) {
        const int k = kk*4 + sub;
        const float a = e[kk];
        #pragma unroll
        for (int g = 0; g < 16; ++g) {
            const float4 t = ld4(&S[k][(g ^ sub) * 4]);
            c[4*g+0] = fmaf(a, t.x, c[4*g+0]);
            c[4*g+1] = fmaf(a, t.y, c[4*g+1]);
            c[4*g+2] = fmaf(a, t.z, c[4*g+2]);
            c[4*g+3] = fmaf(a, t.w, c[4*g+3]);
        }
    }
    #pragma unroll
    for (int d = 0; d < 64; ++d) {
        c[d] += __shfl_xor(c[d], 1);
        c[d] += __shfl_xor(c[d], 2);
    }

    __syncthreads();
    unsigned short* T = (unsigned short*)&S[0][0];   // [64 d][72 m] ushorts
    #pragma unroll
    for (int g = 0; g < 16; ++g) {
        const int d = sub*16 + g;
        T[d*72 + r] = f2bf(c[d]*inv);
    }
    __syncthreads();
    const int d2 = tid >> 2, mg = tid & 3;
    uint4 w0 = *(uint4*)&T[d2*72 + mg*16];
    uint4 w1 = *(uint4*)&T[d2*72 + mg*16 + 8];
    unsigned short* dst = CtxT + (size_t)bh*D_*M_ + (size_t)d2*M_ + mt*64 + mg*16;
    *(uint4*)dst = w0; *(uint4*)(dst+8) = w1;
}

// ---------------- K3: x = DctT @ ctx_t^T, MFMA bf16 ------------------------
__global__ __launch_bounds__(128, 2)
void gemm_out(const unsigned short* __restrict__ DctT, const unsigned short* __restrict__ CtxT,
              float* __restrict__ Out)
{
    __shared__ __align__(16) unsigned short Asw[128*64];
    __shared__ __align__(16) unsigned short Bsw[64*64];
    const int nt = blockIdx.x, bh = blockIdx.y;
    const int n0 = nt*128;
    const unsigned short* ct = CtxT + (size_t)bh*D_*M_;
    float* out = Out + (size_t)bh*N_*D_;
    const int tid = threadIdx.x;
    const int lane = tid & 63, wave = tid >> 6;

    f32x4 acc[4][4];
    #pragma unroll
    for (int i = 0; i < 4; ++i)
        #pragma unroll
        for (int j = 0; j < 4; ++j) { acc[i][j].x=0.f; acc[i][j].y=0.f; acc[i][j].z=0.f; acc[i][j].w=0.f; }

    for (int step = 0; step < 4; ++step) {
        const int k0 = step*64;
        if (step) __syncthreads();
        const int ch = tid & 7;
        #pragma unroll
        for (int rr = 0; rr < 8; ++rr) {
            const int r = (tid>>3) + rr*16;
            const uint4 v = *(const uint4*)(DctT + (size_t)(n0+r)*M_ + k0 + ch*8);
            *(uint4*)((char*)Asw + r*128 + ((ch*16) ^ ((r&7)<<4))) = v;
        }
        #pragma unroll
        for (int rr = 0; rr < 4; ++rr) {
            const int d = (tid>>3) + rr*16;
            const uint4 v = *(const uint4*)(ct + (size_t)d*M_ + k0 + ch*8);
            *(uint4*)((char*)Bsw + d*128 + ((ch*16) ^ (((d>>1)&7)<<4))) = v;
        }
        __syncthreads();
        #pragma unroll
        for (int kh = 0; kh < 2; ++kh) {
            const int colb = kh*64 + (lane>>4)*16;
            short8v a[4], bb[4];
            #pragma unroll
            for (int mf = 0; mf < 4; ++mf) {
                const int r = wave*64 + mf*16 + (lane&15);
                a[mf] = *(const short8v*)((char*)Asw + r*128 + (colb ^ ((r&7)<<4)));
            }
            #pragma unroll
            for (int nf = 0; nf < 4; ++nf) {
                const int r = nf*16 + (lane&15);
                bb[nf] = *(const short8v*)((char*)Bsw + r*128 + (colb ^ (((r>>1)&7)<<4)));
            }
            #pragma unroll
            for (int mf = 0; mf < 4; ++mf)
                #pragma unroll
                for (int nf = 0; nf < 4; ++nf)
                    acc[mf][nf] = __builtin_amdgcn_mfma_f32_16x16x32_bf16(a[mf], bb[nf], acc[mf][nf], 0, 0, 0);
        }
    }
    #pragma unroll
    for (int mf = 0; mf < 4; ++mf)
        #pragma unroll
        for (int nf = 0; nf < 4; ++nf)
            #pragma unroll
            for (int r = 0; r < 4; ++r) {
                const int n = n0 + wave*64 + mf*16 + (lane>>4)*4 + r;
                const int d = nf*16 + (lane&15);
                out[(size_t)n*D_ + d] = acc[mf][nf][r];
            }
}

extern "C" void kernel_launch(void* const* d_in, const int* in_sizes, int n_in,
                              void* d_out, int out_size, void* d_ws, size_t ws_size,
                              hipStream_t stream) {
    const float* Q    = (const float*)d_in[0];
    const float* K    = (const float*)d_in[1];
    const float* V    = (const float*)d_in[2];
    const float* mask = (const float*)d_in[3];
    const float* Dct  = (const float*)d_in[4];
    float* out = (float*)d_out;

    const size_t per = (size_t)BH_ * M_ * D_;          // 1,572,864
    float* wsf = (float*)d_ws;
    float* Qd = wsf;
    float* Kd = Qd + per;
    float* Vd = Kd + per;
    unsigned short* CtxT = (unsigned short*)(Vd + per);  // per ushorts
    unsigned short* DctA = CtxT + per;                   // 524288 (frag-linear)
    unsigned short* DctT = DctA + (size_t)M_ * N_;       // 524288

    dct_prep_kernel<<<dim3(N_/64, M_/64), 256, 0, stream>>>(Dct, DctA, DctT);
    gemm_qkv<<<dim3(576), 256, 0, stream>>>(Q, K, V, mask, DctA, Qd, Kd, Vd);
    attn_kernel<<<dim3(M_/64, BH_), 256, 0, stream>>>(Qd, Kd, Vd, CtxT);
    gemm_out<<<dim3(N_/128, BH_), 128, 0, stream>>>(DctT, CtxT, out);
}

// Round 10
// 122.238 us; speedup vs baseline: 1.3161x; 1.0291x over previous
//
#include <hip/hip_runtime.h>
#include <hip/hip_bf16.h>
#include <cstddef>

#define B_ 8
#define H_ 12
#define N_ 2048
#define D_ 64
#define M_ 256
#define BH_ (B_*H_)

typedef __attribute__((ext_vector_type(8))) short short8v;
typedef __attribute__((ext_vector_type(4))) float f32x4;

static __device__ __forceinline__ float4 ld4(const float* p){ return *(const float4*)p; }

static __device__ __forceinline__ unsigned short f2bf(float x){
    union { float f; unsigned int u; } v; v.f = x;
    unsigned int r = v.u + 0x7FFFu + ((v.u >> 16) & 1u);
    return (unsigned short)(r >> 16);
}
static __device__ __forceinline__ unsigned int pack2(float a, float b){
    return (unsigned int)f2bf(a) | ((unsigned int)f2bf(b) << 16);
}

// ---------------- K0: Dct fp32 -> DctA (MFMA frag-linear bf16) + DctT bf16 ----
// DctA layout: frag (fm, fk) covers rows [16fm,16fm+16) x k [32fk, 32fk+32).
// Element (lane, j): row = 16fm + (lane&15), k = 32fk + (lane>>4)*8 + j.
// Linear: DctA[((fm*64 + fk)*64 + lane)*8 + j]  -> a wave A-frag load is one
// coalesced 1 KB global_load_dwordx4. 1 MB total, L2-resident, shared by all.
__global__ __launch_bounds__(256)
void dct_prep_kernel(const float* __restrict__ Dct, unsigned short* __restrict__ DctA,
                     unsigned short* __restrict__ DctT)
{
    __shared__ __align__(16) unsigned short T[64*72];
    const int n0 = blockIdx.x * 64, m0 = blockIdx.y * 64;
    const int tid = threadIdx.x;
    const int mrow = tid >> 2, ng = tid & 3;
    const int m = m0 + mrow;
    unsigned short h[16];
    #pragma unroll
    for (int j = 0; j < 4; ++j) {
        const float4 t = ld4(Dct + (size_t)m*N_ + n0 + ng*16 + j*4);
        h[4*j+0]=f2bf(t.x); h[4*j+1]=f2bf(t.y); h[4*j+2]=f2bf(t.z); h[4*j+3]=f2bf(t.w);
    }
    unsigned int w[8];
    #pragma unroll
    for (int j = 0; j < 8; ++j) w[j] = (unsigned int)h[2*j] | ((unsigned int)h[2*j+1]<<16);
    const int fm = m >> 4;
    #pragma unroll
    for (int s = 0; s < 2; ++s) {
        const int u = 2*ng + s;                   // 0..7
        const int fk = (n0 >> 5) + (u >> 2);
        const int lane = (m & 15) + (u & 3) * 16;
        unsigned short* dst = DctA + ((size_t)(fm*64 + fk)*64 + lane)*8;
        *(uint4*)dst = *(uint4*)&w[s*4];
    }
    #pragma unroll
    for (int j = 0; j < 16; ++j) T[(ng*16+j)*72 + mrow] = h[j];
    __syncthreads();
    const int n = tid >> 2, mg = tid & 3;
    uint4 a  = *(uint4*)&T[n*72 + mg*16];
    uint4 b2 = *(uint4*)&T[n*72 + mg*16 + 8];
    unsigned short* dt = DctT + (size_t)(n0+n)*M_ + m0 + mg*16;
    *(uint4*)dt = a; *(uint4*)(dt+8) = b2;
}

// ---------------- K1: Qd/Kd/Vd = Dct @ (scaled/masked X), MFMA bf16 ----------
// 576 blocks = (panel=(bh,tz), half). 256 threads (4 waves). Each block: 128 m
// rows x 64 d, full K=2048. BK=128 -> 16 steps (halved step count: testing the
// fixed-cost-per-step hypothesis). Depth-2 A/X register prefetch, lgkmcnt-only
// barrier, XOR-swizzled B LDS (rows 256 B), mask folded into a one-time LDS
// table (broadcast reads at WRITE time).
__global__ __launch_bounds__(256, 2)
void gemm_qkv(const float* __restrict__ Q, const float* __restrict__ K,
              const float* __restrict__ V, const float* __restrict__ mask,
              const unsigned short* __restrict__ DctA,
              float* __restrict__ Qd, float* __restrict__ Kd, float* __restrict__ Vd)
{
    __shared__ __align__(16) unsigned short Bsw[2][64*128];  // 2 x 16 KB, row 256 B
    __shared__ __align__(16) float Msk[N_];                  // 8 KB: smul * mask
    const int wg = blockIdx.x;
    const int id = (wg & 7) * 72 + (wg >> 3);   // 576 = 8 XCD chunks x 72
    const int half  = id & 1;                   // halves of a panel adjacent -> same XCD
    const int panel = id >> 1;                  // 0..287
    const int bh = panel % BH_;
    const int tz = panel / BH_;
    const int b  = bh / H_;
    const float scale = 0.35355339059327373f;
    const float* X; float* Y; float smul; int um;
    if (tz==0)      { X=Q; Y=Qd; smul=scale; um=0; }
    else if (tz==1) { X=K; Y=Kd; smul=scale; um=1; }
    else            { X=V; Y=Vd; smul=1.0f;  um=1; }
    X += (size_t)bh*N_*D_;
    Y += (size_t)bh*M_*D_ + (size_t)half*128*D_;

    const int tid  = threadIdx.x;
    const int lane = tid & 63, wv = tid >> 6;   // 4 waves; wave owns m rows [32wv,32wv+32)
    // A frag base: fm_global = half*8 + wv*2 + mf
    const unsigned short* abase = DctA + (size_t)(half*8 + wv*2)*32768 + (size_t)lane*8;
    // B staging: wave wv covers k rows [32wv,32wv+32) of the 128-k tile; lane = d
    const float* xcol = X + lane;
    const int swz = (lane & 7) << 4;

    f32x4 acc[2][4];
    #pragma unroll
    for (int i = 0; i < 2; ++i)
        #pragma unroll
        for (int j = 0; j < 4; ++j) { acc[i][j].x=0.f; acc[i][j].y=0.f; acc[i][j].z=0.f; acc[i][j].w=0.f; }

    short8v pa[2][4], pb[2][4];   // A-frag prefetch sets [mf][kh]
    float xrA[32], xrB[32];

    #define A_LOAD(P, T) do {                                                 \
        _Pragma("unroll")                                                     \
        for (int mf_ = 0; mf_ < 2; ++mf_)                                     \
            _Pragma("unroll")                                                 \
            for (int kh_ = 0; kh_ < 4; ++kh_)                                 \
                P[mf_][kh_] = *(const short8v*)(abase + (size_t)(mf_*64 + 4*(T)+kh_)*512); \
    } while(0)

    #define X_LOAD(XR, K0) do {                                               \
        const float* xp_ = xcol + (size_t)((K0) + wv*32) * D_;                \
        _Pragma("unroll")                                                     \
        for (int i_ = 0; i_ < 32; ++i_) XR[i_] = xp_[(size_t)i_*D_];          \
    } while(0)

    #define WRITE_B(XR, BUF, K0) do {                                         \
        const float4* mrow_ = (const float4*)&Msk[(K0) + wv*32];              \
        float fmv_[32];                                                       \
        _Pragma("unroll")                                                     \
        for (int j_ = 0; j_ < 8; ++j_) {                                      \
            const float4 t_ = mrow_[j_];                                      \
            fmv_[4*j_]=t_.x; fmv_[4*j_+1]=t_.y; fmv_[4*j_+2]=t_.z; fmv_[4*j_+3]=t_.w; \
        }                                                                     \
        _Pragma("unroll")                                                     \
        for (int c_ = 0; c_ < 4; ++c_) {                                      \
            uint4 w_;                                                         \
            w_.x = pack2(XR[8*c_+0]*fmv_[8*c_+0], XR[8*c_+1]*fmv_[8*c_+1]);   \
            w_.y = pack2(XR[8*c_+2]*fmv_[8*c_+2], XR[8*c_+3]*fmv_[8*c_+3]);   \
            w_.z = pack2(XR[8*c_+4]*fmv_[8*c_+4], XR[8*c_+5]*fmv_[8*c_+5]);   \
            w_.w = pack2(XR[8*c_+6]*fmv_[8*c_+6], XR[8*c_+7]*fmv_[8*c_+7]);   \
            *(uint4*)((char*)&Bsw[BUF][0] + lane*256 + ((wv*64 + c_*16) ^ swz)) = w_; \
        }                                                                     \
    } while(0)

    #define COMPUTE(BUF, P) do {                                              \
        _Pragma("unroll")                                                     \
        for (int kh_ = 0; kh_ < 4; ++kh_) {                                   \
            const int colb_ = kh_*64 + (lane>>4)*16;                          \
            short8v b_[4];                                                    \
            _Pragma("unroll")                                                 \
            for (int nf_ = 0; nf_ < 4; ++nf_) {                               \
                const int rr_ = nf_*16 + (lane&15);                           \
                b_[nf_] = *(const short8v*)((char*)&Bsw[BUF][0] + rr_*256 + (colb_ ^ ((rr_&7)<<4))); \
            }                                                                 \
            _Pragma("unroll")                                                 \
            for (int mf_ = 0; mf_ < 2; ++mf_)                                 \
                _Pragma("unroll")                                             \
                for (int nf_ = 0; nf_ < 4; ++nf_)                             \
                    acc[mf_][nf_] = __builtin_amdgcn_mfma_f32_16x16x32_bf16(P[mf_][kh_], b_[nf_], acc[mf_][nf_], 0, 0, 0); \
        }                                                                     \
    } while(0)

    #define BARJ() do { asm volatile("s_waitcnt lgkmcnt(0)" ::: "memory");    \
                        __builtin_amdgcn_sched_barrier(0);                    \
                        __builtin_amdgcn_s_barrier(); } while(0)

    // ---- prologue: mask table + first two X tiles + A(0)
    {
        #pragma unroll
        for (int c = 0; c < 2; ++c) {
            const int idx = (tid + c*256) * 4;
            float4 v;
            if (um) {
                v = ld4(mask + (size_t)b*N_ + idx);
                v.x *= smul; v.y *= smul; v.z *= smul; v.w *= smul;
            } else { v.x = smul; v.y = smul; v.z = smul; v.w = smul; }
            *(float4*)&Msk[idx] = v;
        }
    }
    A_LOAD(pa, 0);
    X_LOAD(xrA, 0);
    X_LOAD(xrB, 128);
    __syncthreads();               // mask table visible (one-time full drain)
    WRITE_B(xrA, 0, 0);
    BARJ();

    // ---- steady loop t = 0..13 (7 pairs)
    #define STEP_EVEN(T) do {                                                 \
        A_LOAD(pb, (T)+1);                                                    \
        X_LOAD(xrA, ((T)+2)*128);                                             \
        COMPUTE(0, pa);                                                       \
        __builtin_amdgcn_sched_barrier(0);                                    \
        WRITE_B(xrB, 1, ((T)+1)*128);                                         \
        BARJ();                                                               \
    } while(0)
    #define STEP_ODD(T) do {                                                  \
        A_LOAD(pa, (T)+1);                                                    \
        X_LOAD(xrB, ((T)+2)*128);                                             \
        COMPUTE(1, pb);                                                       \
        __builtin_amdgcn_sched_barrier(0);                                    \
        WRITE_B(xrA, 0, ((T)+1)*128);                                         \
        BARJ();                                                               \
    } while(0)

    for (int tb = 0; tb < 14; tb += 2) {
        STEP_EVEN(tb);
        STEP_ODD(tb+1);
    }
    // ---- tail: t=14, t=15
    A_LOAD(pb, 15);
    COMPUTE(0, pa);
    __builtin_amdgcn_sched_barrier(0);
    WRITE_B(xrB, 1, 15*128);
    BARJ();
    COMPUTE(1, pb);

    // epilogue: col = lane&15 (d), row = (lane>>4)*4 + r (m)
    #pragma unroll
    for (int mf = 0; mf < 2; ++mf)
        #pragma unroll
        for (int nf = 0; nf < 4; ++nf)
            #pragma unroll
            for (int r = 0; r < 4; ++r) {
                const int m = wv*32 + mf*16 + (lane>>4)*4 + r;
                const int d = nf*16 + (lane&15);
                Y[(size_t)m*D_ + d] = acc[mf][nf][r];
            }
    #undef A_LOAD
    #undef X_LOAD
    #undef WRITE_B
    #undef COMPUTE
    #undef BARJ
    #undef STEP_EVEN
    #undef STEP_ODD
}

// ---------------- K2: fused energy -> softmax -> ctx (fp32), bf16 transposed out
__global__ __launch_bounds__(256)
void attn_kernel(const float* __restrict__ Qd, const float* __restrict__ Kd,
                 const float* __restrict__ Vd, unsigned short* __restrict__ CtxT)
{
    __shared__ __align__(16) float S[M_][D_];    // 64 KB
    const int mt = blockIdx.x;
    const int bh = blockIdx.y;
    const float* qd = Qd + (size_t)bh * M_ * D_;
    const float* kd = Kd + (size_t)bh * M_ * D_;
    const float* vd = Vd + (size_t)bh * M_ * D_;

    const int tid = threadIdx.x;
    const int r = tid >> 2, sub = tid & 3;
    const int m = mt * 64 + r;

    float q[64];
    #pragma unroll
    for (int g = 0; g < 16; ++g) {
        const float4 t = ld4(qd + (size_t)m * D_ + g*4);
        q[4*g+0] = t.x; q[4*g+1] = t.y; q[4*g+2] = t.z; q[4*g+3] = t.w;
    }

    #pragma unroll
    for (int it = 0; it < 16; ++it) {
        const int i = tid + it*256;
        const int k = i >> 4, g = i & 15;
        const float4 t = ld4(kd + (size_t)i * 4);
        *(float4*)(&S[k][(g ^ (k & 3)) * 4]) = t;
    }
    __syncthreads();

    float e[64];
    #pragma unroll
    for (int kk = 0; kk < 64; ++kk) {
        const int k = kk*4 + sub;
        float acc = 0.f;
        #pragma unroll
        for (int g = 0; g < 16; ++g) {
            const float4 t = ld4(&S[k][(g ^ sub) * 4]);
            acc = fmaf(q[4*g+0], t.x, acc);
            acc = fmaf(q[4*g+1], t.y, acc);
            acc = fmaf(q[4*g+2], t.z, acc);
            acc = fmaf(q[4*g+3], t.w, acc);
        }
        e[kk] = acc;
    }

    float mx = e[0];
    #pragma unroll
    for (int kk = 1; kk < 64; ++kk) mx = fmaxf(mx, e[kk]);
    mx = fmaxf(mx, __shfl_xor(mx, 1));
    mx = fmaxf(mx, __shfl_xor(mx, 2));
    float sum = 0.f;
    #pragma unroll
    for (int kk = 0; kk < 64; ++kk) { e[kk] = __expf(e[kk] - mx); sum += e[kk]; }
    sum += __shfl_xor(sum, 1);
    sum += __shfl_xor(sum, 2);
    const float inv = 1.0f / sum;

    __syncthreads();
    #pragma unroll
    for (int it = 0; it < 16; ++it) {
        const int i = tid + it*256;
        const int k = i >> 4, g = i & 15;
        const float4 t = ld4(vd + (size_t)i * 4);
        *(float4*)(&S[k][(g ^ (k & 3)) * 4]) = t;
    }
    __syncthreads();

    float c[64] = {};
    #pragma unroll
    for (int kk = 0; kk < 64; ++kk) {
        const int k = kk*4 + sub;
        const float a = e[kk];
        #pragma unroll
        for (int g = 0; g < 16; ++g) {
            const float4 t = ld4(&S[k][(g ^ sub) * 4]);
            c[4*g+0] = fmaf(a, t.x, c[4*g+0]);
            c[4*g+1] = fmaf(a, t.y, c[4*g+1]);
            c[4*g+2] = fmaf(a, t.z, c[4*g+2]);
            c[4*g+3] = fmaf(a, t.w, c[4*g+3]);
        }
    }
    #pragma unroll
    for (int d = 0; d < 64; ++d) {
        c[d] += __shfl_xor(c[d], 1);
        c[d] += __shfl_xor(c[d], 2);
    }

    __syncthreads();
    unsigned short* T = (unsigned short*)&S[0][0];   // [64 d][72 m] ushorts
    #pragma unroll
    for (int g = 0; g < 16; ++g) {
        const int d = sub*16 + g;
        T[d*72 + r] = f2bf(c[d]*inv);
    }
    __syncthreads();
    const int d2 = tid >> 2, mg = tid & 3;
    uint4 w0 = *(uint4*)&T[d2*72 + mg*16];
    uint4 w1 = *(uint4*)&T[d2*72 + mg*16 + 8];
    unsigned short* dst = CtxT + (size_t)bh*D_*M_ + (size_t)d2*M_ + mt*64 + mg*16;
    *(uint4*)dst = w0; *(uint4*)(dst+8) = w1;
}

// ---------------- K3: x = DctT @ ctx_t^T, MFMA bf16 ------------------------
__global__ __launch_bounds__(128, 2)
void gemm_out(const unsigned short* __restrict__ DctT, const unsigned short* __restrict__ CtxT,
              float* __restrict__ Out)
{
    __shared__ __align__(16) unsigned short Asw[128*64];
    __shared__ __align__(16) unsigned short Bsw[64*64];
    const int nt = blockIdx.x, bh = blockIdx.y;
    const int n0 = nt*128;
    const unsigned short* ct = CtxT + (size_t)bh*D_*M_;
    float* out = Out + (size_t)bh*N_*D_;
    const int tid = threadIdx.x;
    const int lane = tid & 63, wave = tid >> 6;

    f32x4 acc[4][4];
    #pragma unroll
    for (int i = 0; i < 4; ++i)
        #pragma unroll
        for (int j = 0; j < 4; ++j) { acc[i][j].x=0.f; acc[i][j].y=0.f; acc[i][j].z=0.f; acc[i][j].w=0.f; }

    for (int step = 0; step < 4; ++step) {
        const int k0 = step*64;
        if (step) __syncthreads();
        const int ch = tid & 7;
        #pragma unroll
        for (int rr = 0; rr < 8; ++rr) {
            const int r = (tid>>3) + rr*16;
            const uint4 v = *(const uint4*)(DctT + (size_t)(n0+r)*M_ + k0 + ch*8);
            *(uint4*)((char*)Asw + r*128 + ((ch*16) ^ ((r&7)<<4))) = v;
        }
        #pragma unroll
        for (int rr = 0; rr < 4; ++rr) {
            const int d = (tid>>3) + rr*16;
            const uint4 v = *(const uint4*)(ct + (size_t)d*M_ + k0 + ch*8);
            *(uint4*)((char*)Bsw + d*128 + ((ch*16) ^ (((d>>1)&7)<<4))) = v;
        }
        __syncthreads();
        #pragma unroll
        for (int kh = 0; kh < 2; ++kh) {
            const int colb = kh*64 + (lane>>4)*16;
            short8v a[4], bb[4];
            #pragma unroll
            for (int mf = 0; mf < 4; ++mf) {
                const int r = wave*64 + mf*16 + (lane&15);
                a[mf] = *(const short8v*)((char*)Asw + r*128 + (colb ^ ((r&7)<<4)));
            }
            #pragma unroll
            for (int nf = 0; nf < 4; ++nf) {
                const int r = nf*16 + (lane&15);
                bb[nf] = *(const short8v*)((char*)Bsw + r*128 + (colb ^ (((r>>1)&7)<<4)));
            }
            #pragma unroll
            for (int mf = 0; mf < 4; ++mf)
                #pragma unroll
                for (int nf = 0; nf < 4; ++nf)
                    acc[mf][nf] = __builtin_amdgcn_mfma_f32_16x16x32_bf16(a[mf], bb[nf], acc[mf][nf], 0, 0, 0);
        }
    }
    #pragma unroll
    for (int mf = 0; mf < 4; ++mf)
        #pragma unroll
        for (int nf = 0; nf < 4; ++nf)
            #pragma unroll
            for (int r = 0; r < 4; ++r) {
                const int n = n0 + wave*64 + mf*16 + (lane>>4)*4 + r;
                const int d = nf*16 + (lane&15);
                out[(size_t)n*D_ + d] = acc[mf][nf][r];
            }
}

extern "C" void kernel_launch(void* const* d_in, const int* in_sizes, int n_in,
                              void* d_out, int out_size, void* d_ws, size_t ws_size,
                              hipStream_t stream) {
    const float* Q    = (const float*)d_in[0];
    const float* K    = (const float*)d_in[1];
    const float* V    = (const float*)d_in[2];
    const float* mask = (const float*)d_in[3];
    const float* Dct  = (const float*)d_in[4];
    float* out = (float*)d_out;

    const size_t per = (size_t)BH_ * M_ * D_;          // 1,572,864
    float* wsf = (float*)d_ws;
    float* Qd = wsf;
    float* Kd = Qd + per;
    float* Vd = Kd + per;
    unsigned short* CtxT = (unsigned short*)(Vd + per);  // per ushorts
    unsigned short* DctA = CtxT + per;                   // 524288 (frag-linear)
    unsigned short* DctT = DctA + (size_t)M_ * N_;       // 524288

    dct_prep_kernel<<<dim3(N_/64, M_/64), 256, 0, stream>>>(Dct, DctA, DctT);
    gemm_qkv<<<dim3(576), 256, 0, stream>>>(Q, K, V, mask, DctA, Qd, Kd, Vd);
    attn_kernel<<<dim3(M_/64, BH_), 256, 0, stream>>>(Qd, Kd, Vd, CtxT);
    gemm_out<<<dim3(N_/128, BH_), 128, 0, stream>>>(DctT, CtxT, out);
}